// Round 16
// baseline (633.897 us; speedup 1.0000x reference)
//
#include <hip/hip_runtime.h>
#include <hip/hip_bf16.h>
#include <cstdint>

// Problem dims (fixed by the reference)
#define B_   8192
#define D_   1024
#define O_   1024
#define HE_  2048
#define NN_  7     // decision nodes
#define NL_  8     // leaves / experts
#define HR_  32    // router hidden
#define RC_  224   // NN_*HR_
#define K3_  3072  // router split-GEMM K (hi|hi|lo)
#define MTMAX_ 264 // max total m-tiles over experts (topk=4: <=264)

typedef __attribute__((ext_vector_type(2))) float f32x2;
typedef __attribute__((ext_vector_type(4))) float f32x4;
typedef __attribute__((ext_vector_type(8))) short bf16x8;
typedef __attribute__((ext_vector_type(4))) unsigned short u16x4;
typedef unsigned short u16;
typedef unsigned int u32;

__device__ __forceinline__ u16 f2bf(float f) {
  __hip_bfloat16 h = __float2bfloat16(f);
  return *reinterpret_cast<u16*>(&h);
}
__device__ __forceinline__ float bf2f(u16 u) {
  u32 v = ((u32)u) << 16;
  return *reinterpret_cast<float*>(&v);
}
__device__ __forceinline__ float gelu_exact(float v) {
  return 0.5f * v * (1.0f + erff(v * 0.7071067811865475f));
}
__device__ __forceinline__ void gload16(const void* g, void* l) {
  __builtin_amdgcn_global_load_lds(
      (const __attribute__((address_space(1))) void*)(uintptr_t)g,
      (__attribute__((address_space(3))) void*)(uintptr_t)l,
      16, 0, 0);
}
#define WAITVM(n) asm volatile("s_waitcnt vmcnt(" #n ")" ::: "memory")
#define WAITLGKM0 do { \
  asm volatile("s_waitcnt lgkmcnt(0)" ::: "memory"); \
  __builtin_amdgcn_sched_barrier(0); } while (0)

// scalar-only expert lookup from counts (no runtime-indexed array, rule #20)
__device__ __forceinline__ bool expert_of_tile(
    const int* __restrict__ counts, int mt,
    int& e, int& cnt, long& m0, long& hbase) {
  int tot = 0; e = -1; cnt = 0; int tofe = 0;
#pragma unroll
  for (int f = 0; f < NL_; f++) {
    int c = counts[f];
    int tl = (c + 127) >> 7;
    bool in = (e < 0) && (mt < tot + tl);
    if (in) { e = f; tofe = tot; cnt = c; }
    tot += tl;
  }
  if (e < 0) return false;
  m0 = (long)(mt - tofe) * 128;
  hbase = (long)tofe * 128;
  return true;
}

// ======== fused prep: transposes + x split + router weight pack ============
__global__ __launch_bounds__(256) void prep_kernel(
    const float* __restrict__ x, const float* __restrict__ rW1,
    const float* __restrict__ eW1, const float* __restrict__ eW2,
    u16* __restrict__ Xbs, u16* __restrict__ Wr3,
    u16* __restrict__ W1t, u16* __restrict__ W2t) {
  __shared__ __attribute__((aligned(16))) float tile[64][65];
  int bid = blockIdx.x;
  int t = threadIdx.x;
  if (bid < 8192) {
    const float* in; u16* out; int C, ldo; long in_e, out_e;
    int bx, by, bz;
    if (bid < 4096) {
      in = eW1; out = W1t; C = HE_; ldo = D_;
      in_e = (long)D_ * HE_; out_e = (long)HE_ * D_;
      bx = bid & 31; by = (bid >> 5) & 15; bz = bid >> 9;
    } else {
      int b = bid - 4096;
      in = eW2; out = W2t; C = O_; ldo = HE_;
      in_e = (long)HE_ * O_; out_e = (long)O_ * HE_;
      bx = b & 15; by = (b >> 4) & 31; bz = b >> 9;
    }
    const float* in_p = in + bz * in_e;
    u16* out_p = out + bz * out_e;
    int r0 = by * 64, c0 = bx * 64;
    int cc = t & 63, rbase = t >> 6;
#pragma unroll
    for (int i = 0; i < 16; i++) {
      int rr = rbase + i * 4;
      tile[rr][cc] = in_p[(long)(r0 + rr) * C + c0 + cc];
    }
    __syncthreads();
    int r2 = (t & 31) * 2, cj = t >> 5;
#pragma unroll
    for (int i = 0; i < 8; i++) {
      int c = cj * 8 + i;
      u32 u = (u32)f2bf(tile[r2][c]) | ((u32)f2bf(tile[r2 + 1][c]) << 16);
      *reinterpret_cast<u32*>(out_p + (long)(c0 + c) * ldo + r0 + r2) = u;
    }
  } else if (bid < 16384) {
    size_t i = ((size_t)(bid - 8192) * 256 + t) * 4;
    size_t row = i >> 10;
    int col = (int)(i & 1023);
    f32x4 f = *reinterpret_cast<const f32x4*>(x + i);
    u16x4 hi, lo;
#pragma unroll
    for (int j = 0; j < 4; j++) {
      hi[j] = f2bf(f[j]);
      lo[j] = f2bf(f[j] - bf2f(hi[j]));
    }
    u16* base = Xbs + row * 2048 + col;
    *reinterpret_cast<u16x4*>(base)        = hi;
    *reinterpret_cast<u16x4*>(base + 1024) = lo;
  } else {
    size_t i = ((size_t)(bid - 16384) * 256 + t) * 4;  // over 256*3072
    int c = (int)(i / K3_), k = (int)(i % K3_);
    int j = k >> 10, kk = k & 1023;
    u16x4 o;
    if (c < RC_) {
      int node = c >> 5, h = c & 31;
      const float* src = rW1 + ((size_t)node * 1024 + kk) * HR_ + h;
#pragma unroll
      for (int q = 0; q < 4; q++) {
        float f = src[q * HR_];
        u16 hi = f2bf(f);
        o[q] = (j == 1) ? f2bf(f - bf2f(hi)) : hi;
      }
    } else {
      o[0] = 0; o[1] = 0; o[2] = 0; o[3] = 0;
    }
    *reinterpret_cast<u16x4*>(Wr3 + i) = o;
  }
}

// ---- router GEMM, split-K=4: H1p[s] = Xbs(mapped) @ Wr3^T  (raw, no gelu) -
__global__ __launch_bounds__(256, 2) void router_gemm_kernel(
    const u16* __restrict__ Xbs, const u16* __restrict__ Bm,
    float* __restrict__ H1p) {
  __shared__ __attribute__((aligned(16))) u16 lA[128 * 32];
  __shared__ __attribute__((aligned(16))) u16 lB[128 * 32];
  int tid = threadIdx.x;
  int gid = blockIdx.x;
  int cpx = gridDim.x >> 3;
  gid = (gid & 7) * cpx + (gid >> 3);
  int s = gid >> 7;                  // split id 0..3
  int rem = gid & 127;
  int band = rem >> 4, inb = rem & 15;
  long m0 = (long)(band * 8 + (inb & 7)) * 128;
  long n0 = (long)(inb >> 3) * 128;
  int wid = tid >> 6, lane = tid & 63;
  int wm = wid >> 1, wn = wid & 1;
  f32x4 acc[4][4];
#pragma unroll
  for (int m = 0; m < 4; m++)
#pragma unroll
    for (int n = 0; n < 4; n++) acc[m][n] = (f32x4){0.f, 0.f, 0.f, 0.f};
  int lr = lane & 15, lk = (lane >> 4) * 8;
  int srow = tid >> 2, soff = (tid & 3) * 8;
  const u16* Bb = Bm + n0 * K3_;
  int kbeg = s * 768, kend = kbeg + 768;
  for (int k0 = kbeg; k0 < kend; k0 += 32) {
    int ca = (k0 < 1024) ? k0 : k0 - 1024;   // hi / hi / lo remap
    gload16(Xbs + (m0 + srow) * 2048 + ca + soff, &lA[tid * 8]);
    gload16(Xbs + (m0 + 64 + srow) * 2048 + ca + soff, &lA[(256 + tid) * 8]);
    gload16(Bb + (long)srow * K3_ + k0 + soff, &lB[tid * 8]);
    gload16(Bb + (long)(64 + srow) * K3_ + k0 + soff, &lB[(256 + tid) * 8]);
    __syncthreads();
    bf16x8 af[4], bfr[4];
#pragma unroll
    for (int m = 0; m < 4; m++)
      af[m] = *reinterpret_cast<const bf16x8*>(&lA[(wm * 64 + m * 16 + lr) * 32 + lk]);
#pragma unroll
    for (int n = 0; n < 4; n++)
      bfr[n] = *reinterpret_cast<const bf16x8*>(&lB[(wn * 64 + n * 16 + lr) * 32 + lk]);
#pragma unroll
    for (int m = 0; m < 4; m++)
#pragma unroll
      for (int n = 0; n < 4; n++)
        acc[m][n] = __builtin_amdgcn_mfma_f32_16x16x32_bf16(af[m], bfr[n], acc[m][n], 0, 0, 0);
    __syncthreads();
  }
  int lq = lane >> 4;
#pragma unroll
  for (int m = 0; m < 4; m++)
#pragma unroll
    for (int n = 0; n < 4; n++)
#pragma unroll
      for (int j = 0; j < 4; j++) {
        long row = m0 + wm * 64 + m * 16 + lq * 4 + j;
        long col = n0 + wn * 64 + n * 16 + lr;
        if (col < RC_)
          H1p[((long)s * B_ + row) * RC_ + col] = acc[m][n][j];
      }
}

// -------- router layer 2: sum split-K partials + bias + gelu, softmax, -----
__global__ __launch_bounds__(256) void router_logits_kernel(
    const float* __restrict__ H1p, const float* __restrict__ rb1,
    const float* __restrict__ rW2, const float* __restrict__ rb2,
    const int* __restrict__ topk_ptr, float* __restrict__ P) {
  int b = blockIdx.x * 256 + threadIdx.x;
  float dec[NN_][2];
#pragma unroll
  for (int n = 0; n < NN_; n++) {
    float l0 = rb2[n * 2], l1 = rb2[n * 2 + 1];
#pragma unroll
    for (int r4 = 0; r4 < HR_; r4 += 4) {
      int c = n * HR_ + r4;
      f32x4 hs = *reinterpret_cast<const f32x4*>(&H1p[((long)0 * B_ + b) * RC_ + c]);
#pragma unroll
      for (int s = 1; s < 4; s++)
        hs += *reinterpret_cast<const f32x4*>(&H1p[((long)s * B_ + b) * RC_ + c]);
      f32x4 bv = *reinterpret_cast<const f32x4*>(rb1 + c);
#pragma unroll
      for (int j = 0; j < 4; j++) {
        float hv = gelu_exact(hs[j] + bv[j]);
        l0 += hv * rW2[(c + j) * 2];
        l1 += hv * rW2[(c + j) * 2 + 1];
      }
    }
    float mx = fmaxf(l0, l1);
    float e0 = expf(l0 - mx), e1 = expf(l1 - mx);
    float sm = e0 + e1;
    dec[n][0] = e0 / sm; dec[n][1] = e1 / sm;
  }
  float v[NL_];
#pragma unroll
  for (int L = 0; L < NL_; L++)
    v[L] = dec[0][L >> 2] * dec[1 + (L >> 2)][(L >> 1) & 1] * dec[3 + (L >> 1)][L & 1];
  int tk = *topk_ptr;
  float p[NL_];
  if (tk < NL_) {
    float s = 0.f;
    bool keep[NL_];
#pragma unroll
    for (int e = 0; e < NL_; e++) {
      int rank = 0;
#pragma unroll
      for (int j = 0; j < NL_; j++)
        rank += ((v[j] > v[e]) || (v[j] == v[e] && j < e)) ? 1 : 0;
      keep[e] = rank < tk;
      if (keep[e]) s += v[e];
    }
    float inv = 1.f / (s + 1e-8f);
#pragma unroll
    for (int e = 0; e < NL_; e++) p[e] = keep[e] ? v[e] * inv : 0.f;
  } else {
#pragma unroll
    for (int e = 0; e < NL_; e++) p[e] = v[e];
  }
#pragma unroll
  for (int e = 0; e < NL_; e++) P[(long)b * NL_ + e] = p[e];
}

// ======== fused tail: yinit (blocks 0..8191) + compact (blocks 8192..8199) =
__global__ __launch_bounds__(256) void tail_kernel(
    const float* __restrict__ P, const float* __restrict__ eb2,
    float* __restrict__ y, int* __restrict__ idx, int* __restrict__ counts) {
  __shared__ int wsum[4];
  __shared__ int sbase;
  int t = threadIdx.x;
  if (blockIdx.x < 8192) {
    size_t i = ((size_t)blockIdx.x * 256 + t) * 4;
    size_t row = i >> 10;
    int col = (int)(i & 1023);
    f32x4 s = (f32x4){0.f, 0.f, 0.f, 0.f};
#pragma unroll
    for (int e = 0; e < NL_; e++) {
      float pe = P[row * NL_ + e];
      f32x4 w = *reinterpret_cast<const f32x4*>(eb2 + (size_t)e * O_ + col);
      s += w * pe;
    }
    *reinterpret_cast<f32x4*>(y + i) = s;
  } else {
    int e = blockIdx.x - 8192;
    int wave = t >> 6, lane = t & 63;
    if (t == 0) sbase = 0;
    __syncthreads();
    for (int c0 = 0; c0 < B_; c0 += 256) {
      int r = c0 + t;
      bool f = P[(long)r * NL_ + e] > 0.f;
      unsigned long long mask = __ballot(f);
      int intra = __popcll(mask & ((1ULL << lane) - 1ULL));
      if (lane == 0) wsum[wave] = __popcll(mask);
      __syncthreads();
      int wpre = 0;
#pragma unroll
      for (int w = 0; w < 4; w++) wpre += (w < wave) ? wsum[w] : 0;
      int tot = wsum[0] + wsum[1] + wsum[2] + wsum[3];
      if (f) idx[(long)e * B_ + sbase + wpre + intra] = r;
      __syncthreads();
      if (t == 0) sbase += tot;
      __syncthreads();
    }
    if (t == 0) counts[e] = sbase;
  }
}

// ======== grouped sparse expert GEMM1: BK=32, TRIPLE buffer, depth-2 =======
// 128x128 tile, 4 waves 2x2. 3 x 16KB = 48KB LDS (3 blocks/CU), 12 loads in
// flight steady-state (~2 iterations of latency cover for gathered rows).
// Wait ladder: t<NT-2 -> vmcnt(8) (tile t = oldest 4 of <=12), t==NT-2 ->
// vmcnt(4), last -> vmcnt(0). Stage into just-consumed buffer AFTER the
// second barrier (reads are in registers at each wave's lgkmcnt(0)).
__global__ __launch_bounds__(256, 2) void gemme1_kernel(
    const u16* __restrict__ Xbs, const u16* __restrict__ W1t,
    const float* __restrict__ eb1, const float* __restrict__ P,
    u16* __restrict__ Hall, const int* __restrict__ idx,
    const int* __restrict__ counts) {
  __shared__ __attribute__((aligned(16))) u16 lA[3][128 * 32];
  __shared__ __attribute__((aligned(16))) u16 lB[3][128 * 32];
  int tid = threadIdx.x;
  int gid = blockIdx.x;
  int cpx = gridDim.x >> 3;
  gid = (gid & 7) * cpx + (gid >> 3);      // XCD swizzle (grid%8==0)
  int mt = gid >> 4, nt = gid & 15;
  int e, cnt; long m0, hbase;
  if (!expert_of_tile(counts, mt, e, cnt, m0, hbase)) return;
  long n0 = (long)nt * 128;
  const int* idxe = idx + (long)e * B_;
  int wid = tid >> 6, lane = tid & 63;
  int wm = wid >> 1, wn = wid & 1;
  f32x4 acc[4][4];
#pragma unroll
  for (int m = 0; m < 4; m++)
#pragma unroll
    for (int n = 0; n < 4; n++) acc[m][n] = (f32x4){0.f, 0.f, 0.f, 0.f};
  int lr = lane & 15, lkg = lane >> 4;
  // staging: 128 rows x 4 chunks(16B) = 512 slots per tensor, 2 rounds each
  const u16* gA[2]; const u16* gB[2]; int lds_o[2];
  const u16* Bb = W1t + ((size_t)e * HE_ + n0) * D_;
#pragma unroll
  for (int i = 0; i < 2; i++) {
    int sidx = tid + i * 256;
    int r = sidx >> 2, j = sidx & 3;
    int so = ((j ^ ((r >> 1) & 3)) << 3);   // pre-swizzled source col (elems)
    int gi = (m0 + r < cnt) ? idxe[m0 + r] : 0;
    gA[i] = Xbs + (long)gi * 2048 + so;
    gB[i] = Bb + (long)r * D_ + so;
    lds_o[i] = sidx * 8;
  }
  // read-side frag byte offsets: row r, k-group lkg at slot lkg^((r>>1)&3)
  int foA[4], foB[4];
#pragma unroll
  for (int m = 0; m < 4; m++) {
    int r = wm * 64 + m * 16 + lr;
    foA[m] = r * 64 + (((lkg ^ ((r >> 1) & 3))) << 4);
  }
#pragma unroll
  for (int n = 0; n < 4; n++) {
    int r = wn * 64 + n * 16 + lr;
    foB[n] = r * 64 + (((lkg ^ ((r >> 1) & 3))) << 4);
  }
#define STAGE1(buf, k0) do { _Pragma("unroll") \
  for (int i_ = 0; i_ < 2; i_++) gload16(gA[i_] + (k0), &lA[buf][lds_o[i_]]); \
  _Pragma("unroll") \
  for (int i_ = 0; i_ < 2; i_++) gload16(gB[i_] + (k0), &lB[buf][lds_o[i_]]); \
  } while (0)
  STAGE1(0, 0); STAGE1(1, 32); STAGE1(2, 64);   // depth-2 prefetch (12 loads)
  int cur = 0;
  constexpr int NT = D_ / 32;
  for (int t = 0; t < NT; ++t) {
    if (t < NT - 2)      WAITVM(8);   // tile t's 4 loads done; 8 stay in flight
    else if (t == NT - 2) WAITVM(4);
    else                 WAITVM(0);
    __builtin_amdgcn_s_barrier();
    __builtin_amdgcn_sched_barrier(0);
    const char* pa = (const char*)lA[cur];
    const char* pb = (const char*)lB[cur];
    bf16x8 af[4], bfr[4];
#pragma unroll
    for (int m = 0; m < 4; m++)
      af[m] = *reinterpret_cast<const bf16x8*>(pa + foA[m]);
#pragma unroll
    for (int n = 0; n < 4; n++)
      bfr[n] = *reinterpret_cast<const bf16x8*>(pb + foB[n]);
    WAITLGKM0;
    __builtin_amdgcn_s_setprio(1);
#pragma unroll
    for (int m = 0; m < 4; m++)
#pragma unroll
      for (int n = 0; n < 4; n++)
        acc[m][n] = __builtin_amdgcn_mfma_f32_16x16x32_bf16(af[m], bfr[n], acc[m][n], 0, 0, 0);
    __builtin_amdgcn_s_setprio(0);
    __builtin_amdgcn_s_barrier();   // all waves' reads of buf[cur] complete
    __builtin_amdgcn_sched_barrier(0);
    if (t + 3 < NT) STAGE1(cur, (t + 3) * 32);   // refill just-consumed buf
    cur = (cur == 2) ? 0 : cur + 1;
  }
#undef STAGE1
  int lq = lane >> 4;
#pragma unroll
  for (int m = 0; m < 4; m++) {
#pragma unroll
    for (int j = 0; j < 4; j++) {
      long lrow = m0 + wm * 64 + m * 16 + lq * 4 + j;
      if (lrow >= cnt) continue;
      int orow = idxe[lrow];
      float pw = P[(long)orow * NL_ + e];
#pragma unroll
      for (int n = 0; n < 4; n++) {
        long col = n0 + wn * 64 + n * 16 + lr;
        float g = gelu_exact(acc[m][n][j] + eb1[(size_t)e * HE_ + col]);
        Hall[(hbase + lrow) * HE_ + col] = f2bf(g * pw);
      }
    }
  }
}

// ======== grouped sparse expert GEMM2: counted-vmcnt double buffer =========
// A = Hall compact rows (K=2048), B = W2t[e][o][k] (ldb=2048 contiguous).
__global__ __launch_bounds__(256, 2) void gemme2_kernel(
    const u16* __restrict__ Hall, const u16* __restrict__ W2t,
    float* __restrict__ y, const int* __restrict__ idx,
    const int* __restrict__ counts) {
  __shared__ __attribute__((aligned(16))) u16 lA[2][128 * 64];
  __shared__ __attribute__((aligned(16))) u16 lB[2][128 * 64];
  int tid = threadIdx.x;
  int gid = blockIdx.x;
  int cpx = gridDim.x >> 3;
  gid = (gid & 7) * cpx + (gid >> 3);
  int mt = gid >> 3, nt = gid & 7;
  int e, cnt; long m0, hbase;
  if (!expert_of_tile(counts, mt, e, cnt, m0, hbase)) return;
  long n0 = (long)nt * 128;
  const int* idxe = idx + (long)e * B_;
  int wid = tid >> 6, lane = tid & 63;
  int wm = wid >> 1, wn = wid & 1;
  f32x4 acc[4][4];
#pragma unroll
  for (int m = 0; m < 4; m++)
#pragma unroll
    for (int n = 0; n < 4; n++) acc[m][n] = (f32x4){0.f, 0.f, 0.f, 0.f};
  int lr = lane & 15, lkg = lane >> 4;
  const u16* Ab = Hall + (hbase + m0) * HE_;
  const u16* Bb = W2t + ((size_t)e * O_ + n0) * HE_;
  const u16* gA[4]; const u16* gB[4]; int lds_o[4];
#pragma unroll
  for (int i = 0; i < 4; i++) {
    int sidx = tid + i * 256;
    int r = sidx >> 3, j = sidx & 7;
    int so = ((j ^ (r & 7)) << 3);
    gA[i] = Ab + (long)r * HE_ + so;
    gB[i] = Bb + (long)r * HE_ + so;
    lds_o[i] = sidx * 8;
  }
  int foA[4][2], foB[4][2];
#pragma unroll
  for (int m = 0; m < 4; m++) {
    int r = wm * 64 + m * 16 + lr;
#pragma unroll
    for (int kk = 0; kk < 2; kk++)
      foA[m][kk] = r * 128 + ((((kk * 4 + lkg) ^ (r & 7))) << 4);
  }
#pragma unroll
  for (int n = 0; n < 4; n++) {
    int r = wn * 64 + n * 16 + lr;
#pragma unroll
    for (int kk = 0; kk < 2; kk++)
      foB[n][kk] = r * 128 + ((((kk * 4 + lkg) ^ (r & 7))) << 4);
  }
#define STAGE2(buf, k0) do { _Pragma("unroll") \
  for (int i_ = 0; i_ < 4; i_++) gload16(gA[i_] + (k0), &lA[buf][lds_o[i_]]); \
  _Pragma("unroll") \
  for (int i_ = 0; i_ < 4; i_++) gload16(gB[i_] + (k0), &lB[buf][lds_o[i_]]); \
  } while (0)
  STAGE2(0, 0);
  int cur = 0;
  constexpr int NT = HE_ / 64;
  for (int t = 0; t < NT; ++t) {
    if (t + 1 < NT) {
      STAGE2(cur ^ 1, (t + 1) * 64);
      WAITVM(8);                 // tile t's 8 loads done; new 8 stay in flight
    } else {
      WAITVM(0);
    }
    __builtin_amdgcn_s_barrier();
    __builtin_amdgcn_sched_barrier(0);
    const char* pa = (const char*)lA[cur];
    const char* pb = (const char*)lB[cur];
    bf16x8 af[4][2], bfr[4][2];
#pragma unroll
    for (int m = 0; m < 4; m++) {
      af[m][0] = *reinterpret_cast<const bf16x8*>(pa + foA[m][0]);
      af[m][1] = *reinterpret_cast<const bf16x8*>(pa + foA[m][1]);
    }
#pragma unroll
    for (int n = 0; n < 4; n++) {
      bfr[n][0] = *reinterpret_cast<const bf16x8*>(pb + foB[n][0]);
      bfr[n][1] = *reinterpret_cast<const bf16x8*>(pb + foB[n][1]);
    }
    WAITLGKM0;
    __builtin_amdgcn_s_setprio(1);
#pragma unroll
    for (int m = 0; m < 4; m++)
#pragma unroll
      for (int n = 0; n < 4; n++) {
        acc[m][n] = __builtin_amdgcn_mfma_f32_16x16x32_bf16(af[m][0], bfr[n][0], acc[m][n], 0, 0, 0);
        acc[m][n] = __builtin_amdgcn_mfma_f32_16x16x32_bf16(af[m][1], bfr[n][1], acc[m][n], 0, 0, 0);
      }
    __builtin_amdgcn_s_setprio(0);
    __builtin_amdgcn_s_barrier();   // all waves' reads of buf[cur] complete
    __builtin_amdgcn_sched_barrier(0);
    cur ^= 1;
  }
#undef STAGE2
  int lq = lane >> 4;
#pragma unroll
  for (int m = 0; m < 4; m++) {
#pragma unroll
    for (int j = 0; j < 4; j++) {
      long lrow = m0 + wm * 64 + m * 16 + lq * 4 + j;
      if (lrow >= cnt) continue;
      long orow = idxe[lrow];
#pragma unroll
      for (int n = 0; n < 4; n++) {
        long col = n0 + wn * 64 + n * 16 + lr;
        unsafeAtomicAdd(&y[orow * O_ + col], acc[m][n][j]);
      }
    }
  }
}

extern "C" void kernel_launch(void* const* d_in, const int* in_sizes, int n_in,
                              void* d_out, int out_size, void* d_ws, size_t ws_size,
                              hipStream_t stream) {
  (void)in_sizes; (void)n_in; (void)out_size; (void)ws_size;
  const float* x   = (const float*)d_in[0];
  const float* rW1 = (const float*)d_in[1];
  const float* rb1 = (const float*)d_in[2];
  const float* rW2 = (const float*)d_in[3];
  const float* rb2 = (const float*)d_in[4];
  const float* eW1 = (const float*)d_in[5];
  const float* eb1 = (const float*)d_in[6];
  const float* eW2 = (const float*)d_in[7];
  const float* eb2 = (const float*)d_in[8];
  const int*  topk = (const int*)d_in[9];
  float* y = (float*)d_out;
  float* P = y + (size_t)B_ * O_;   // leaf_probs live in d_out tail

  // ws layout (high-water ~239 MiB, proven to fit):
  char* ws = (char*)d_ws;
  u16*  Xbs = (u16*)ws;                                   // 32 MiB [hi|lo]
  u16*  W1t = (u16*)(ws + 33554432);                      // 32 MiB
  u16*  W2t = (u16*)(ws + 67108864);                      // 32 MiB [e][o][k]
  int*  idx    = (int*)(ws + 100663296);                  // 256 KiB
  int*  counts = (int*)(ws + 100925440);                  // 32 B
  char* hreg   = ws + 100925952;                          // Hall region
  u16*  Hall = (u16*)hreg;                                // 33792x2048 bf16
  u16*  Wr3  = (u16*)hreg;                                // dead before Hall
  float* H1p = (float*)(hreg + 2097152);                  // dead before Hall

  // fused prep: 4096 (W1t) + 4096 (W2t) + 8192 (Xbs) + 768 (Wr3) blocks
  prep_kernel<<<17152, 256, 0, stream>>>(x, rW1, eW1, eW2, Xbs, Wr3, W1t, W2t);
  router_gemm_kernel<<<512, 256, 0, stream>>>(Xbs, Wr3, H1p);
  router_logits_kernel<<<B_ / 256, 256, 0, stream>>>(H1p, rb1, rW2, rb2, topk, P);
  // fused tail: 8192 yinit blocks + 8 compact blocks
  tail_kernel<<<8200, 256, 0, stream>>>(P, eb2, y, idx, counts);

  // grouped sparse expert GEMMs (one dispatch each, full GPU)
  gemme1_kernel<<<MTMAX_ * 16, 256, 0, stream>>>(
      Xbs, W1t, eb1, P, Hall, idx, counts);
  gemme2_kernel<<<MTMAX_ * 8, 256, 0, stream>>>(
      Hall, W2t, y, idx, counts);
}

// Round 17
// 621.355 us; speedup vs baseline: 1.0202x; 1.0202x over previous
//
#include <hip/hip_runtime.h>
#include <hip/hip_bf16.h>
#include <cstdint>

// Problem dims (fixed by the reference)
#define B_   8192
#define D_   1024
#define O_   1024
#define HE_  2048
#define NN_  7     // decision nodes
#define NL_  8     // leaves / experts
#define HR_  32    // router hidden
#define RC_  224   // NN_*HR_
#define K3_  3072  // router split-GEMM K (hi|hi|lo)
#define MTMAX_ 264 // max total m-tiles over experts (topk=4: <=264)

typedef __attribute__((ext_vector_type(2))) float f32x2;
typedef __attribute__((ext_vector_type(4))) float f32x4;
typedef __attribute__((ext_vector_type(8))) short bf16x8;
typedef __attribute__((ext_vector_type(4))) unsigned short u16x4;
typedef unsigned short u16;
typedef unsigned int u32;

__device__ __forceinline__ u16 f2bf(float f) {
  __hip_bfloat16 h = __float2bfloat16(f);
  return *reinterpret_cast<u16*>(&h);
}
__device__ __forceinline__ float bf2f(u16 u) {
  u32 v = ((u32)u) << 16;
  return *reinterpret_cast<float*>(&v);
}
__device__ __forceinline__ float gelu_exact(float v) {
  return 0.5f * v * (1.0f + erff(v * 0.7071067811865475f));
}
__device__ __forceinline__ void gload16(const void* g, void* l) {
  __builtin_amdgcn_global_load_lds(
      (const __attribute__((address_space(1))) void*)(uintptr_t)g,
      (__attribute__((address_space(3))) void*)(uintptr_t)l,
      16, 0, 0);
}
#define WAITVM(n) asm volatile("s_waitcnt vmcnt(" #n ")" ::: "memory")
#define WAITLGKM0 do { \
  asm volatile("s_waitcnt lgkmcnt(0)" ::: "memory"); \
  __builtin_amdgcn_sched_barrier(0); } while (0)

// scalar-only expert lookup from counts (no runtime-indexed array, rule #20)
__device__ __forceinline__ bool expert_of_tile(
    const int* __restrict__ counts, int mt,
    int& e, int& cnt, long& m0, long& hbase) {
  int tot = 0; e = -1; cnt = 0; int tofe = 0;
#pragma unroll
  for (int f = 0; f < NL_; f++) {
    int c = counts[f];
    int tl = (c + 127) >> 7;
    bool in = (e < 0) && (mt < tot + tl);
    if (in) { e = f; tofe = tot; cnt = c; }
    tot += tl;
  }
  if (e < 0) return false;
  m0 = (long)(mt - tofe) * 128;
  hbase = (long)tofe * 128;
  return true;
}

// ======== fused prep: transposes + x split + router weight pack ============
__global__ __launch_bounds__(256) void prep_kernel(
    const float* __restrict__ x, const float* __restrict__ rW1,
    const float* __restrict__ eW1, const float* __restrict__ eW2,
    u16* __restrict__ Xbs, u16* __restrict__ Wr3,
    u16* __restrict__ W1t, u16* __restrict__ W2t) {
  __shared__ __attribute__((aligned(16))) float tile[64][65];
  int bid = blockIdx.x;
  int t = threadIdx.x;
  if (bid < 8192) {
    const float* in; u16* out; int C, ldo; long in_e, out_e;
    int bx, by, bz;
    if (bid < 4096) {
      in = eW1; out = W1t; C = HE_; ldo = D_;
      in_e = (long)D_ * HE_; out_e = (long)HE_ * D_;
      bx = bid & 31; by = (bid >> 5) & 15; bz = bid >> 9;
    } else {
      int b = bid - 4096;
      in = eW2; out = W2t; C = O_; ldo = HE_;
      in_e = (long)HE_ * O_; out_e = (long)O_ * HE_;
      bx = b & 15; by = (b >> 4) & 31; bz = b >> 9;
    }
    const float* in_p = in + bz * in_e;
    u16* out_p = out + bz * out_e;
    int r0 = by * 64, c0 = bx * 64;
    int cc = t & 63, rbase = t >> 6;
#pragma unroll
    for (int i = 0; i < 16; i++) {
      int rr = rbase + i * 4;
      tile[rr][cc] = in_p[(long)(r0 + rr) * C + c0 + cc];
    }
    __syncthreads();
    int r2 = (t & 31) * 2, cj = t >> 5;
#pragma unroll
    for (int i = 0; i < 8; i++) {
      int c = cj * 8 + i;
      u32 u = (u32)f2bf(tile[r2][c]) | ((u32)f2bf(tile[r2 + 1][c]) << 16);
      *reinterpret_cast<u32*>(out_p + (long)(c0 + c) * ldo + r0 + r2) = u;
    }
  } else if (bid < 16384) {
    size_t i = ((size_t)(bid - 8192) * 256 + t) * 4;
    size_t row = i >> 10;
    int col = (int)(i & 1023);
    f32x4 f = *reinterpret_cast<const f32x4*>(x + i);
    u16x4 hi, lo;
#pragma unroll
    for (int j = 0; j < 4; j++) {
      hi[j] = f2bf(f[j]);
      lo[j] = f2bf(f[j] - bf2f(hi[j]));
    }
    u16* base = Xbs + row * 2048 + col;
    *reinterpret_cast<u16x4*>(base)        = hi;
    *reinterpret_cast<u16x4*>(base + 1024) = lo;
  } else {
    size_t i = ((size_t)(bid - 16384) * 256 + t) * 4;  // over 256*3072
    int c = (int)(i / K3_), k = (int)(i % K3_);
    int j = k >> 10, kk = k & 1023;
    u16x4 o;
    if (c < RC_) {
      int node = c >> 5, h = c & 31;
      const float* src = rW1 + ((size_t)node * 1024 + kk) * HR_ + h;
#pragma unroll
      for (int q = 0; q < 4; q++) {
        float f = src[q * HR_];
        u16 hi = f2bf(f);
        o[q] = (j == 1) ? f2bf(f - bf2f(hi)) : hi;
      }
    } else {
      o[0] = 0; o[1] = 0; o[2] = 0; o[3] = 0;
    }
    *reinterpret_cast<u16x4*>(Wr3 + i) = o;
  }
}

// ---- router GEMM, split-K=4: H1p[s] = Xbs(mapped) @ Wr3^T  (raw, no gelu) -
__global__ __launch_bounds__(256, 2) void router_gemm_kernel(
    const u16* __restrict__ Xbs, const u16* __restrict__ Bm,
    float* __restrict__ H1p) {
  __shared__ __attribute__((aligned(16))) u16 lA[128 * 32];
  __shared__ __attribute__((aligned(16))) u16 lB[128 * 32];
  int tid = threadIdx.x;
  int gid = blockIdx.x;
  int cpx = gridDim.x >> 3;
  gid = (gid & 7) * cpx + (gid >> 3);
  int s = gid >> 7;                  // split id 0..3
  int rem = gid & 127;
  int band = rem >> 4, inb = rem & 15;
  long m0 = (long)(band * 8 + (inb & 7)) * 128;
  long n0 = (long)(inb >> 3) * 128;
  int wid = tid >> 6, lane = tid & 63;
  int wm = wid >> 1, wn = wid & 1;
  f32x4 acc[4][4];
#pragma unroll
  for (int m = 0; m < 4; m++)
#pragma unroll
    for (int n = 0; n < 4; n++) acc[m][n] = (f32x4){0.f, 0.f, 0.f, 0.f};
  int lr = lane & 15, lk = (lane >> 4) * 8;
  int srow = tid >> 2, soff = (tid & 3) * 8;
  const u16* Bb = Bm + n0 * K3_;
  int kbeg = s * 768, kend = kbeg + 768;
  for (int k0 = kbeg; k0 < kend; k0 += 32) {
    int ca = (k0 < 1024) ? k0 : k0 - 1024;   // hi / hi / lo remap
    gload16(Xbs + (m0 + srow) * 2048 + ca + soff, &lA[tid * 8]);
    gload16(Xbs + (m0 + 64 + srow) * 2048 + ca + soff, &lA[(256 + tid) * 8]);
    gload16(Bb + (long)srow * K3_ + k0 + soff, &lB[tid * 8]);
    gload16(Bb + (long)(64 + srow) * K3_ + k0 + soff, &lB[(256 + tid) * 8]);
    __syncthreads();
    bf16x8 af[4], bfr[4];
#pragma unroll
    for (int m = 0; m < 4; m++)
      af[m] = *reinterpret_cast<const bf16x8*>(&lA[(wm * 64 + m * 16 + lr) * 32 + lk]);
#pragma unroll
    for (int n = 0; n < 4; n++)
      bfr[n] = *reinterpret_cast<const bf16x8*>(&lB[(wn * 64 + n * 16 + lr) * 32 + lk]);
#pragma unroll
    for (int m = 0; m < 4; m++)
#pragma unroll
      for (int n = 0; n < 4; n++)
        acc[m][n] = __builtin_amdgcn_mfma_f32_16x16x32_bf16(af[m], bfr[n], acc[m][n], 0, 0, 0);
    __syncthreads();
  }
  int lq = lane >> 4;
#pragma unroll
  for (int m = 0; m < 4; m++)
#pragma unroll
    for (int n = 0; n < 4; n++)
#pragma unroll
      for (int j = 0; j < 4; j++) {
        long row = m0 + wm * 64 + m * 16 + lq * 4 + j;
        long col = n0 + wn * 64 + n * 16 + lr;
        if (col < RC_)
          H1p[((long)s * B_ + row) * RC_ + col] = acc[m][n][j];
      }
}

// -------- router layer 2: sum split-K partials + bias + gelu, softmax, -----
__global__ __launch_bounds__(256) void router_logits_kernel(
    const float* __restrict__ H1p, const float* __restrict__ rb1,
    const float* __restrict__ rW2, const float* __restrict__ rb2,
    const int* __restrict__ topk_ptr, float* __restrict__ P) {
  int b = blockIdx.x * 256 + threadIdx.x;
  float dec[NN_][2];
#pragma unroll
  for (int n = 0; n < NN_; n++) {
    float l0 = rb2[n * 2], l1 = rb2[n * 2 + 1];
#pragma unroll
    for (int r4 = 0; r4 < HR_; r4 += 4) {
      int c = n * HR_ + r4;
      f32x4 hs = *reinterpret_cast<const f32x4*>(&H1p[((long)0 * B_ + b) * RC_ + c]);
#pragma unroll
      for (int s = 1; s < 4; s++)
        hs += *reinterpret_cast<const f32x4*>(&H1p[((long)s * B_ + b) * RC_ + c]);
      f32x4 bv = *reinterpret_cast<const f32x4*>(rb1 + c);
#pragma unroll
      for (int j = 0; j < 4; j++) {
        float hv = gelu_exact(hs[j] + bv[j]);
        l0 += hv * rW2[(c + j) * 2];
        l1 += hv * rW2[(c + j) * 2 + 1];
      }
    }
    float mx = fmaxf(l0, l1);
    float e0 = expf(l0 - mx), e1 = expf(l1 - mx);
    float sm = e0 + e1;
    dec[n][0] = e0 / sm; dec[n][1] = e1 / sm;
  }
  float v[NL_];
#pragma unroll
  for (int L = 0; L < NL_; L++)
    v[L] = dec[0][L >> 2] * dec[1 + (L >> 2)][(L >> 1) & 1] * dec[3 + (L >> 1)][L & 1];
  int tk = *topk_ptr;
  float p[NL_];
  if (tk < NL_) {
    float s = 0.f;
    bool keep[NL_];
#pragma unroll
    for (int e = 0; e < NL_; e++) {
      int rank = 0;
#pragma unroll
      for (int j = 0; j < NL_; j++)
        rank += ((v[j] > v[e]) || (v[j] == v[e] && j < e)) ? 1 : 0;
      keep[e] = rank < tk;
      if (keep[e]) s += v[e];
    }
    float inv = 1.f / (s + 1e-8f);
#pragma unroll
    for (int e = 0; e < NL_; e++) p[e] = keep[e] ? v[e] * inv : 0.f;
  } else {
#pragma unroll
    for (int e = 0; e < NL_; e++) p[e] = v[e];
  }
#pragma unroll
  for (int e = 0; e < NL_; e++) P[(long)b * NL_ + e] = p[e];
}

// ======== fused tail: yinit (blocks 0..8191) + compact (blocks 8192..8199) =
__global__ __launch_bounds__(256) void tail_kernel(
    const float* __restrict__ P, const float* __restrict__ eb2,
    float* __restrict__ y, int* __restrict__ idx, int* __restrict__ counts) {
  __shared__ int wsum[4];
  __shared__ int sbase;
  int t = threadIdx.x;
  if (blockIdx.x < 8192) {
    size_t i = ((size_t)blockIdx.x * 256 + t) * 4;
    size_t row = i >> 10;
    int col = (int)(i & 1023);
    f32x4 s = (f32x4){0.f, 0.f, 0.f, 0.f};
#pragma unroll
    for (int e = 0; e < NL_; e++) {
      float pe = P[row * NL_ + e];
      f32x4 w = *reinterpret_cast<const f32x4*>(eb2 + (size_t)e * O_ + col);
      s += w * pe;
    }
    *reinterpret_cast<f32x4*>(y + i) = s;
  } else {
    int e = blockIdx.x - 8192;
    int wave = t >> 6, lane = t & 63;
    if (t == 0) sbase = 0;
    __syncthreads();
    for (int c0 = 0; c0 < B_; c0 += 256) {
      int r = c0 + t;
      bool f = P[(long)r * NL_ + e] > 0.f;
      unsigned long long mask = __ballot(f);
      int intra = __popcll(mask & ((1ULL << lane) - 1ULL));
      if (lane == 0) wsum[wave] = __popcll(mask);
      __syncthreads();
      int wpre = 0;
#pragma unroll
      for (int w = 0; w < 4; w++) wpre += (w < wave) ? wsum[w] : 0;
      int tot = wsum[0] + wsum[1] + wsum[2] + wsum[3];
      if (f) idx[(long)e * B_ + sbase + wpre + intra] = r;
      __syncthreads();
      if (t == 0) sbase += tot;
      __syncthreads();
    }
    if (t == 0) counts[e] = sbase;
  }
}

// ======== grouped sparse expert GEMM1: BK=32 counted-vmcnt double buffer ===
// 128x128 tile, 4 waves 2x2. dbuf = 2 x 16KB = 32KB LDS (keeps ~3 blocks/CU
// TLP) + gemme2's counted-vmcnt overlap. Per tile: STAGE(buf^1,t+1)=4 gloads
// -> vmcnt(4) -> barrier -> 8 ds_read_b128 -> lgkmcnt(0) -> 16 MFMA ->
// barrier. Swizzle for 4-chunk rows: slot = j ^ ((r>>1)&3).
// (R16's depth-2 triple buffer REGRESSED: more in-flight gathered streams
//  raise L2 pressure faster than they add latency cover. Depth-1 is optimal.)
__global__ __launch_bounds__(256, 2) void gemme1_kernel(
    const u16* __restrict__ Xbs, const u16* __restrict__ W1t,
    const float* __restrict__ eb1, const float* __restrict__ P,
    u16* __restrict__ Hall, const int* __restrict__ idx,
    const int* __restrict__ counts) {
  __shared__ __attribute__((aligned(16))) u16 lA[2][128 * 32];
  __shared__ __attribute__((aligned(16))) u16 lB[2][128 * 32];
  int tid = threadIdx.x;
  int gid = blockIdx.x;
  int cpx = gridDim.x >> 3;
  gid = (gid & 7) * cpx + (gid >> 3);      // XCD swizzle (grid%8==0)
  int mt = gid >> 4, nt = gid & 15;
  int e, cnt; long m0, hbase;
  if (!expert_of_tile(counts, mt, e, cnt, m0, hbase)) return;
  long n0 = (long)nt * 128;
  const int* idxe = idx + (long)e * B_;
  int wid = tid >> 6, lane = tid & 63;
  int wm = wid >> 1, wn = wid & 1;
  f32x4 acc[4][4];
#pragma unroll
  for (int m = 0; m < 4; m++)
#pragma unroll
    for (int n = 0; n < 4; n++) acc[m][n] = (f32x4){0.f, 0.f, 0.f, 0.f};
  int lr = lane & 15, lkg = lane >> 4;
  // staging: 128 rows x 4 chunks(16B) = 512 slots per tensor, 2 rounds each
  const u16* gA[2]; const u16* gB[2]; int lds_o[2];
  const u16* Bb = W1t + ((size_t)e * HE_ + n0) * D_;
#pragma unroll
  for (int i = 0; i < 2; i++) {
    int sidx = tid + i * 256;
    int r = sidx >> 2, j = sidx & 3;
    int so = ((j ^ ((r >> 1) & 3)) << 3);   // pre-swizzled source col (elems)
    int gi = (m0 + r < cnt) ? idxe[m0 + r] : 0;
    gA[i] = Xbs + (long)gi * 2048 + so;
    gB[i] = Bb + (long)r * D_ + so;
    lds_o[i] = sidx * 8;
  }
  // read-side frag byte offsets: row r, k-group lkg at slot lkg^((r>>1)&3)
  int foA[4], foB[4];
#pragma unroll
  for (int m = 0; m < 4; m++) {
    int r = wm * 64 + m * 16 + lr;
    foA[m] = r * 64 + (((lkg ^ ((r >> 1) & 3))) << 4);
  }
#pragma unroll
  for (int n = 0; n < 4; n++) {
    int r = wn * 64 + n * 16 + lr;
    foB[n] = r * 64 + (((lkg ^ ((r >> 1) & 3))) << 4);
  }
#define STAGE1(buf, k0) do { _Pragma("unroll") \
  for (int i_ = 0; i_ < 2; i_++) gload16(gA[i_] + (k0), &lA[buf][lds_o[i_]]); \
  _Pragma("unroll") \
  for (int i_ = 0; i_ < 2; i_++) gload16(gB[i_] + (k0), &lB[buf][lds_o[i_]]); \
  } while (0)
  STAGE1(0, 0);
  int cur = 0;
  constexpr int NT = D_ / 32;
  for (int t = 0; t < NT; ++t) {
    if (t + 1 < NT) {
      STAGE1(cur ^ 1, (t + 1) * 32);
      WAITVM(4);                 // tile t's 4 loads done; new 4 stay in flight
    } else {
      WAITVM(0);
    }
    __builtin_amdgcn_s_barrier();
    __builtin_amdgcn_sched_barrier(0);
    const char* pa = (const char*)lA[cur];
    const char* pb = (const char*)lB[cur];
    bf16x8 af[4], bfr[4];
#pragma unroll
    for (int m = 0; m < 4; m++)
      af[m] = *reinterpret_cast<const bf16x8*>(pa + foA[m]);
#pragma unroll
    for (int n = 0; n < 4; n++)
      bfr[n] = *reinterpret_cast<const bf16x8*>(pb + foB[n]);
    WAITLGKM0;
    __builtin_amdgcn_s_setprio(1);
#pragma unroll
    for (int m = 0; m < 4; m++)
#pragma unroll
      for (int n = 0; n < 4; n++)
        acc[m][n] = __builtin_amdgcn_mfma_f32_16x16x32_bf16(af[m], bfr[n], acc[m][n], 0, 0, 0);
    __builtin_amdgcn_s_setprio(0);
    __builtin_amdgcn_s_barrier();   // all waves' reads of buf[cur] complete
    __builtin_amdgcn_sched_barrier(0);
    cur ^= 1;
  }
#undef STAGE1
  int lq = lane >> 4;
#pragma unroll
  for (int m = 0; m < 4; m++) {
#pragma unroll
    for (int j = 0; j < 4; j++) {
      long lrow = m0 + wm * 64 + m * 16 + lq * 4 + j;
      if (lrow >= cnt) continue;
      int orow = idxe[lrow];
      float pw = P[(long)orow * NL_ + e];
#pragma unroll
      for (int n = 0; n < 4; n++) {
        long col = n0 + wn * 64 + n * 16 + lr;
        float g = gelu_exact(acc[m][n][j] + eb1[(size_t)e * HE_ + col]);
        Hall[(hbase + lrow) * HE_ + col] = f2bf(g * pw);
      }
    }
  }
}

// ======== grouped sparse expert GEMM2: counted-vmcnt double buffer =========
// A = Hall compact rows (K=2048), B = W2t[e][o][k] (ldb=2048 contiguous).
__global__ __launch_bounds__(256, 2) void gemme2_kernel(
    const u16* __restrict__ Hall, const u16* __restrict__ W2t,
    float* __restrict__ y, const int* __restrict__ idx,
    const int* __restrict__ counts) {
  __shared__ __attribute__((aligned(16))) u16 lA[2][128 * 64];
  __shared__ __attribute__((aligned(16))) u16 lB[2][128 * 64];
  int tid = threadIdx.x;
  int gid = blockIdx.x;
  int cpx = gridDim.x >> 3;
  gid = (gid & 7) * cpx + (gid >> 3);
  int mt = gid >> 3, nt = gid & 7;
  int e, cnt; long m0, hbase;
  if (!expert_of_tile(counts, mt, e, cnt, m0, hbase)) return;
  long n0 = (long)nt * 128;
  const int* idxe = idx + (long)e * B_;
  int wid = tid >> 6, lane = tid & 63;
  int wm = wid >> 1, wn = wid & 1;
  f32x4 acc[4][4];
#pragma unroll
  for (int m = 0; m < 4; m++)
#pragma unroll
    for (int n = 0; n < 4; n++) acc[m][n] = (f32x4){0.f, 0.f, 0.f, 0.f};
  int lr = lane & 15, lkg = lane >> 4;
  const u16* Ab = Hall + (hbase + m0) * HE_;
  const u16* Bb = W2t + ((size_t)e * O_ + n0) * HE_;
  const u16* gA[4]; const u16* gB[4]; int lds_o[4];
#pragma unroll
  for (int i = 0; i < 4; i++) {
    int sidx = tid + i * 256;
    int r = sidx >> 3, j = sidx & 7;
    int so = ((j ^ (r & 7)) << 3);
    gA[i] = Ab + (long)r * HE_ + so;
    gB[i] = Bb + (long)r * HE_ + so;
    lds_o[i] = sidx * 8;
  }
  int foA[4][2], foB[4][2];
#pragma unroll
  for (int m = 0; m < 4; m++) {
    int r = wm * 64 + m * 16 + lr;
#pragma unroll
    for (int kk = 0; kk < 2; kk++)
      foA[m][kk] = r * 128 + ((((kk * 4 + lkg) ^ (r & 7))) << 4);
  }
#pragma unroll
  for (int n = 0; n < 4; n++) {
    int r = wn * 64 + n * 16 + lr;
#pragma unroll
    for (int kk = 0; kk < 2; kk++)
      foB[n][kk] = r * 128 + ((((kk * 4 + lkg) ^ (r & 7))) << 4);
  }
#define STAGE2(buf, k0) do { _Pragma("unroll") \
  for (int i_ = 0; i_ < 4; i_++) gload16(gA[i_] + (k0), &lA[buf][lds_o[i_]]); \
  _Pragma("unroll") \
  for (int i_ = 0; i_ < 4; i_++) gload16(gB[i_] + (k0), &lB[buf][lds_o[i_]]); \
  } while (0)
  STAGE2(0, 0);
  int cur = 0;
  constexpr int NT = HE_ / 64;
  for (int t = 0; t < NT; ++t) {
    if (t + 1 < NT) {
      STAGE2(cur ^ 1, (t + 1) * 64);
      WAITVM(8);                 // tile t's 8 loads done; new 8 stay in flight
    } else {
      WAITVM(0);
    }
    __builtin_amdgcn_s_barrier();
    __builtin_amdgcn_sched_barrier(0);
    const char* pa = (const char*)lA[cur];
    const char* pb = (const char*)lB[cur];
    bf16x8 af[4][2], bfr[4][2];
#pragma unroll
    for (int m = 0; m < 4; m++) {
      af[m][0] = *reinterpret_cast<const bf16x8*>(pa + foA[m][0]);
      af[m][1] = *reinterpret_cast<const bf16x8*>(pa + foA[m][1]);
    }
#pragma unroll
    for (int n = 0; n < 4; n++) {
      bfr[n][0] = *reinterpret_cast<const bf16x8*>(pb + foB[n][0]);
      bfr[n][1] = *reinterpret_cast<const bf16x8*>(pb + foB[n][1]);
    }
    WAITLGKM0;
    __builtin_amdgcn_s_setprio(1);
#pragma unroll
    for (int m = 0; m < 4; m++)
#pragma unroll
      for (int n = 0; n < 4; n++) {
        acc[m][n] = __builtin_amdgcn_mfma_f32_16x16x32_bf16(af[m][0], bfr[n][0], acc[m][n], 0, 0, 0);
        acc[m][n] = __builtin_amdgcn_mfma_f32_16x16x32_bf16(af[m][1], bfr[n][1], acc[m][n], 0, 0, 0);
      }
    __builtin_amdgcn_s_setprio(0);
    __builtin_amdgcn_s_barrier();   // all waves' reads of buf[cur] complete
    __builtin_amdgcn_sched_barrier(0);
    cur ^= 1;
  }
#undef STAGE2
  int lq = lane >> 4;
#pragma unroll
  for (int m = 0; m < 4; m++) {
#pragma unroll
    for (int j = 0; j < 4; j++) {
      long lrow = m0 + wm * 64 + m * 16 + lq * 4 + j;
      if (lrow >= cnt) continue;
      long orow = idxe[lrow];
#pragma unroll
      for (int n = 0; n < 4; n++) {
        long col = n0 + wn * 64 + n * 16 + lr;
        unsafeAtomicAdd(&y[orow * O_ + col], acc[m][n][j]);
      }
    }
  }
}

extern "C" void kernel_launch(void* const* d_in, const int* in_sizes, int n_in,
                              void* d_out, int out_size, void* d_ws, size_t ws_size,
                              hipStream_t stream) {
  (void)in_sizes; (void)n_in; (void)out_size; (void)ws_size;
  const float* x   = (const float*)d_in[0];
  const float* rW1 = (const float*)d_in[1];
  const float* rb1 = (const float*)d_in[2];
  const float* rW2 = (const float*)d_in[3];
  const float* rb2 = (const float*)d_in[4];
  const float* eW1 = (const float*)d_in[5];
  const float* eb1 = (const float*)d_in[6];
  const float* eW2 = (const float*)d_in[7];
  const float* eb2 = (const float*)d_in[8];
  const int*  topk = (const int*)d_in[9];
  float* y = (float*)d_out;
  float* P = y + (size_t)B_ * O_;   // leaf_probs live in d_out tail

  // ws layout (high-water ~239 MiB, proven to fit):
  char* ws = (char*)d_ws;
  u16*  Xbs = (u16*)ws;                                   // 32 MiB [hi|lo]
  u16*  W1t = (u16*)(ws + 33554432);                      // 32 MiB
  u16*  W2t = (u16*)(ws + 67108864);                      // 32 MiB [e][o][k]
  int*  idx    = (int*)(ws + 100663296);                  // 256 KiB
  int*  counts = (int*)(ws + 100925440);                  // 32 B
  char* hreg   = ws + 100925952;                          // Hall region
  u16*  Hall = (u16*)hreg;                                // 33792x2048 bf16
  u16*  Wr3  = (u16*)hreg;                                // dead before Hall
  float* H1p = (float*)(hreg + 2097152);                  // dead before Hall

  // fused prep: 4096 (W1t) + 4096 (W2t) + 8192 (Xbs) + 768 (Wr3) blocks
  prep_kernel<<<17152, 256, 0, stream>>>(x, rW1, eW1, eW2, Xbs, Wr3, W1t, W2t);
  router_gemm_kernel<<<512, 256, 0, stream>>>(Xbs, Wr3, H1p);
  router_logits_kernel<<<B_ / 256, 256, 0, stream>>>(H1p, rb1, rW2, rb2, topk, P);
  // fused tail: 8192 yinit blocks + 8 compact blocks
  tail_kernel<<<8200, 256, 0, stream>>>(P, eb2, y, idx, counts);

  // grouped sparse expert GEMMs (one dispatch each, full GPU)
  gemme1_kernel<<<MTMAX_ * 16, 256, 0, stream>>>(
      Xbs, W1t, eb1, P, Hall, idx, counts);
  gemme2_kernel<<<MTMAX_ * 8, 256, 0, stream>>>(
      Hall, W2t, y, idx, counts);
}

// Round 18
// 593.451 us; speedup vs baseline: 1.0682x; 1.0470x over previous
//
#include <hip/hip_runtime.h>
#include <hip/hip_bf16.h>
#include <cstdint>

// Problem dims (fixed by the reference)
#define B_   8192
#define D_   1024
#define O_   1024
#define HE_  2048
#define NN_  7     // decision nodes
#define NL_  8     // leaves / experts
#define HR_  32    // router hidden
#define RC_  224   // NN_*HR_
#define K3_  3072  // router split-GEMM K (hi|hi|lo)
#define MTMAX_ 264 // max total m-tiles over experts (topk=4: <=264)

typedef __attribute__((ext_vector_type(2))) float f32x2;
typedef __attribute__((ext_vector_type(4))) float f32x4;
typedef __attribute__((ext_vector_type(8))) short bf16x8;
typedef __attribute__((ext_vector_type(4))) unsigned short u16x4;
typedef unsigned short u16;
typedef unsigned int u32;

__device__ __forceinline__ u16 f2bf(float f) {
  __hip_bfloat16 h = __float2bfloat16(f);
  return *reinterpret_cast<u16*>(&h);
}
__device__ __forceinline__ float bf2f(u16 u) {
  u32 v = ((u32)u) << 16;
  return *reinterpret_cast<float*>(&v);
}
__device__ __forceinline__ float gelu_exact(float v) {
  return 0.5f * v * (1.0f + erff(v * 0.7071067811865475f));
}
// tanh-approx gelu (|err| ~3e-4 < bf16 rounding of H). Used ONLY on the
// continuous expert path (H) — router keeps exact erff (top-k decisions).
__device__ __forceinline__ float gelu_fast(float x) {
  float u = x * x;
  float z = x * (0.7978845608f + 0.0356774081f * u);   // c1*x + c1*c2*x^3
  float t = __expf(2.0f * z);                          // v_exp; inf/0 safe
  float th = 1.0f - 2.0f / (t + 1.0f);
  return 0.5f * x * (1.0f + th);
}
__device__ __forceinline__ void gload16(const void* g, void* l) {
  __builtin_amdgcn_global_load_lds(
      (const __attribute__((address_space(1))) void*)(uintptr_t)g,
      (__attribute__((address_space(3))) void*)(uintptr_t)l,
      16, 0, 0);
}
#define WAITVM(n) asm volatile("s_waitcnt vmcnt(" #n ")" ::: "memory")
#define WAITLGKM0 do { \
  asm volatile("s_waitcnt lgkmcnt(0)" ::: "memory"); \
  __builtin_amdgcn_sched_barrier(0); } while (0)

// scalar-only expert lookup from counts (no runtime-indexed array, rule #20)
__device__ __forceinline__ bool expert_of_tile(
    const int* __restrict__ counts, int mt,
    int& e, int& cnt, long& m0, long& hbase) {
  int tot = 0; e = -1; cnt = 0; int tofe = 0;
#pragma unroll
  for (int f = 0; f < NL_; f++) {
    int c = counts[f];
    int tl = (c + 127) >> 7;
    bool in = (e < 0) && (mt < tot + tl);
    if (in) { e = f; tofe = tot; cnt = c; }
    tot += tl;
  }
  if (e < 0) return false;
  m0 = (long)(mt - tofe) * 128;
  hbase = (long)tofe * 128;
  return true;
}

// ======== fused prep: transposes + x split + router weight pack ============
__global__ __launch_bounds__(256) void prep_kernel(
    const float* __restrict__ x, const float* __restrict__ rW1,
    const float* __restrict__ eW1, const float* __restrict__ eW2,
    u16* __restrict__ Xbs, u16* __restrict__ Wr3,
    u16* __restrict__ W1t, u16* __restrict__ W2t) {
  __shared__ __attribute__((aligned(16))) float tile[64][65];
  int bid = blockIdx.x;
  int t = threadIdx.x;
  if (bid < 8192) {
    const float* in; u16* out; int C, ldo; long in_e, out_e;
    int bx, by, bz;
    if (bid < 4096) {
      in = eW1; out = W1t; C = HE_; ldo = D_;
      in_e = (long)D_ * HE_; out_e = (long)HE_ * D_;
      bx = bid & 31; by = (bid >> 5) & 15; bz = bid >> 9;
    } else {
      int b = bid - 4096;
      in = eW2; out = W2t; C = O_; ldo = HE_;
      in_e = (long)HE_ * O_; out_e = (long)O_ * HE_;
      bx = b & 15; by = (b >> 4) & 31; bz = b >> 9;
    }
    const float* in_p = in + bz * in_e;
    u16* out_p = out + bz * out_e;
    int r0 = by * 64, c0 = bx * 64;
    int cc = t & 63, rbase = t >> 6;
#pragma unroll
    for (int i = 0; i < 16; i++) {
      int rr = rbase + i * 4;
      tile[rr][cc] = in_p[(long)(r0 + rr) * C + c0 + cc];
    }
    __syncthreads();
    int r2 = (t & 31) * 2, cj = t >> 5;
#pragma unroll
    for (int i = 0; i < 8; i++) {
      int c = cj * 8 + i;
      u32 u = (u32)f2bf(tile[r2][c]) | ((u32)f2bf(tile[r2 + 1][c]) << 16);
      *reinterpret_cast<u32*>(out_p + (long)(c0 + c) * ldo + r0 + r2) = u;
    }
  } else if (bid < 16384) {
    size_t i = ((size_t)(bid - 8192) * 256 + t) * 4;
    size_t row = i >> 10;
    int col = (int)(i & 1023);
    f32x4 f = *reinterpret_cast<const f32x4*>(x + i);
    u16x4 hi, lo;
#pragma unroll
    for (int j = 0; j < 4; j++) {
      hi[j] = f2bf(f[j]);
      lo[j] = f2bf(f[j] - bf2f(hi[j]));
    }
    u16* base = Xbs + row * 2048 + col;
    *reinterpret_cast<u16x4*>(base)        = hi;
    *reinterpret_cast<u16x4*>(base + 1024) = lo;
  } else {
    size_t i = ((size_t)(bid - 16384) * 256 + t) * 4;  // over 256*3072
    int c = (int)(i / K3_), k = (int)(i % K3_);
    int j = k >> 10, kk = k & 1023;
    u16x4 o;
    if (c < RC_) {
      int node = c >> 5, h = c & 31;
      const float* src = rW1 + ((size_t)node * 1024 + kk) * HR_ + h;
#pragma unroll
      for (int q = 0; q < 4; q++) {
        float f = src[q * HR_];
        u16 hi = f2bf(f);
        o[q] = (j == 1) ? f2bf(f - bf2f(hi)) : hi;
      }
    } else {
      o[0] = 0; o[1] = 0; o[2] = 0; o[3] = 0;
    }
    *reinterpret_cast<u16x4*>(Wr3 + i) = o;
  }
}

// ---- router GEMM, split-K=4: H1p[s] = Xbs(mapped) @ Wr3^T  (raw, no gelu) -
__global__ __launch_bounds__(256, 2) void router_gemm_kernel(
    const u16* __restrict__ Xbs, const u16* __restrict__ Bm,
    float* __restrict__ H1p) {
  __shared__ __attribute__((aligned(16))) u16 lA[128 * 32];
  __shared__ __attribute__((aligned(16))) u16 lB[128 * 32];
  int tid = threadIdx.x;
  int gid = blockIdx.x;
  int cpx = gridDim.x >> 3;
  gid = (gid & 7) * cpx + (gid >> 3);
  int s = gid >> 7;                  // split id 0..3
  int rem = gid & 127;
  int band = rem >> 4, inb = rem & 15;
  long m0 = (long)(band * 8 + (inb & 7)) * 128;
  long n0 = (long)(inb >> 3) * 128;
  int wid = tid >> 6, lane = tid & 63;
  int wm = wid >> 1, wn = wid & 1;
  f32x4 acc[4][4];
#pragma unroll
  for (int m = 0; m < 4; m++)
#pragma unroll
    for (int n = 0; n < 4; n++) acc[m][n] = (f32x4){0.f, 0.f, 0.f, 0.f};
  int lr = lane & 15, lk = (lane >> 4) * 8;
  int srow = tid >> 2, soff = (tid & 3) * 8;
  const u16* Bb = Bm + n0 * K3_;
  int kbeg = s * 768, kend = kbeg + 768;
  for (int k0 = kbeg; k0 < kend; k0 += 32) {
    int ca = (k0 < 1024) ? k0 : k0 - 1024;   // hi / hi / lo remap
    gload16(Xbs + (m0 + srow) * 2048 + ca + soff, &lA[tid * 8]);
    gload16(Xbs + (m0 + 64 + srow) * 2048 + ca + soff, &lA[(256 + tid) * 8]);
    gload16(Bb + (long)srow * K3_ + k0 + soff, &lB[tid * 8]);
    gload16(Bb + (long)(64 + srow) * K3_ + k0 + soff, &lB[(256 + tid) * 8]);
    __syncthreads();
    bf16x8 af[4], bfr[4];
#pragma unroll
    for (int m = 0; m < 4; m++)
      af[m] = *reinterpret_cast<const bf16x8*>(&lA[(wm * 64 + m * 16 + lr) * 32 + lk]);
#pragma unroll
    for (int n = 0; n < 4; n++)
      bfr[n] = *reinterpret_cast<const bf16x8*>(&lB[(wn * 64 + n * 16 + lr) * 32 + lk]);
#pragma unroll
    for (int m = 0; m < 4; m++)
#pragma unroll
      for (int n = 0; n < 4; n++)
        acc[m][n] = __builtin_amdgcn_mfma_f32_16x16x32_bf16(af[m], bfr[n], acc[m][n], 0, 0, 0);
    __syncthreads();
  }
  int lq = lane >> 4;
#pragma unroll
  for (int m = 0; m < 4; m++)
#pragma unroll
    for (int n = 0; n < 4; n++)
#pragma unroll
      for (int j = 0; j < 4; j++) {
        long row = m0 + wm * 64 + m * 16 + lq * 4 + j;
        long col = n0 + wn * 64 + n * 16 + lr;
        if (col < RC_)
          H1p[((long)s * B_ + row) * RC_ + col] = acc[m][n][j];
      }
}

// -------- router layer 2: sum split-K partials + bias + gelu, softmax, -----
// NOTE: keeps EXACT erff gelu — feeds top-k decisions (discontinuous).
__global__ __launch_bounds__(256) void router_logits_kernel(
    const float* __restrict__ H1p, const float* __restrict__ rb1,
    const float* __restrict__ rW2, const float* __restrict__ rb2,
    const int* __restrict__ topk_ptr, float* __restrict__ P) {
  int b = blockIdx.x * 256 + threadIdx.x;
  float dec[NN_][2];
#pragma unroll
  for (int n = 0; n < NN_; n++) {
    float l0 = rb2[n * 2], l1 = rb2[n * 2 + 1];
#pragma unroll
    for (int r4 = 0; r4 < HR_; r4 += 4) {
      int c = n * HR_ + r4;
      f32x4 hs = *reinterpret_cast<const f32x4*>(&H1p[((long)0 * B_ + b) * RC_ + c]);
#pragma unroll
      for (int s = 1; s < 4; s++)
        hs += *reinterpret_cast<const f32x4*>(&H1p[((long)s * B_ + b) * RC_ + c]);
      f32x4 bv = *reinterpret_cast<const f32x4*>(rb1 + c);
#pragma unroll
      for (int j = 0; j < 4; j++) {
        float hv = gelu_exact(hs[j] + bv[j]);
        l0 += hv * rW2[(c + j) * 2];
        l1 += hv * rW2[(c + j) * 2 + 1];
      }
    }
    float mx = fmaxf(l0, l1);
    float e0 = expf(l0 - mx), e1 = expf(l1 - mx);
    float sm = e0 + e1;
    dec[n][0] = e0 / sm; dec[n][1] = e1 / sm;
  }
  float v[NL_];
#pragma unroll
  for (int L = 0; L < NL_; L++)
    v[L] = dec[0][L >> 2] * dec[1 + (L >> 2)][(L >> 1) & 1] * dec[3 + (L >> 1)][L & 1];
  int tk = *topk_ptr;
  float p[NL_];
  if (tk < NL_) {
    float s = 0.f;
    bool keep[NL_];
#pragma unroll
    for (int e = 0; e < NL_; e++) {
      int rank = 0;
#pragma unroll
      for (int j = 0; j < NL_; j++)
        rank += ((v[j] > v[e]) || (v[j] == v[e] && j < e)) ? 1 : 0;
      keep[e] = rank < tk;
      if (keep[e]) s += v[e];
    }
    float inv = 1.f / (s + 1e-8f);
#pragma unroll
    for (int e = 0; e < NL_; e++) p[e] = keep[e] ? v[e] * inv : 0.f;
  } else {
#pragma unroll
    for (int e = 0; e < NL_; e++) p[e] = v[e];
  }
#pragma unroll
  for (int e = 0; e < NL_; e++) P[(long)b * NL_ + e] = p[e];
}

// ======== fused tail: yinit (blocks 0..8191) + compact (blocks 8192..8199) =
__global__ __launch_bounds__(256) void tail_kernel(
    const float* __restrict__ P, const float* __restrict__ eb2,
    float* __restrict__ y, int* __restrict__ idx, int* __restrict__ counts) {
  __shared__ int wsum[4];
  __shared__ int sbase;
  int t = threadIdx.x;
  if (blockIdx.x < 8192) {
    size_t i = ((size_t)blockIdx.x * 256 + t) * 4;
    size_t row = i >> 10;
    int col = (int)(i & 1023);
    f32x4 s = (f32x4){0.f, 0.f, 0.f, 0.f};
#pragma unroll
    for (int e = 0; e < NL_; e++) {
      float pe = P[row * NL_ + e];
      f32x4 w = *reinterpret_cast<const f32x4*>(eb2 + (size_t)e * O_ + col);
      s += w * pe;
    }
    *reinterpret_cast<f32x4*>(y + i) = s;
  } else {
    int e = blockIdx.x - 8192;
    int wave = t >> 6, lane = t & 63;
    if (t == 0) sbase = 0;
    __syncthreads();
    for (int c0 = 0; c0 < B_; c0 += 256) {
      int r = c0 + t;
      bool f = P[(long)r * NL_ + e] > 0.f;
      unsigned long long mask = __ballot(f);
      int intra = __popcll(mask & ((1ULL << lane) - 1ULL));
      if (lane == 0) wsum[wave] = __popcll(mask);
      __syncthreads();
      int wpre = 0;
#pragma unroll
      for (int w = 0; w < 4; w++) wpre += (w < wave) ? wsum[w] : 0;
      int tot = wsum[0] + wsum[1] + wsum[2] + wsum[3];
      if (f) idx[(long)e * B_ + sbase + wpre + intra] = r;
      __syncthreads();
      if (t == 0) sbase += tot;
      __syncthreads();
    }
    if (t == 0) counts[e] = sbase;
  }
}

// ======== grouped sparse expert GEMM1: BK=32 counted-vmcnt double buffer ===
// 128x128 tile, 4 waves 2x2. dbuf = 2 x 16KB = 32KB LDS (keeps ~3 blocks/CU
// TLP) + counted-vmcnt overlap. Epilogue uses gelu_fast (tanh approx, error
// below bf16 rounding of H) — cuts the erff VALU cost that drove VALUBusy 47%.
__global__ __launch_bounds__(256, 2) void gemme1_kernel(
    const u16* __restrict__ Xbs, const u16* __restrict__ W1t,
    const float* __restrict__ eb1, const float* __restrict__ P,
    u16* __restrict__ Hall, const int* __restrict__ idx,
    const int* __restrict__ counts) {
  __shared__ __attribute__((aligned(16))) u16 lA[2][128 * 32];
  __shared__ __attribute__((aligned(16))) u16 lB[2][128 * 32];
  int tid = threadIdx.x;
  int gid = blockIdx.x;
  int cpx = gridDim.x >> 3;
  gid = (gid & 7) * cpx + (gid >> 3);      // XCD swizzle (grid%8==0)
  int mt = gid >> 4, nt = gid & 15;
  int e, cnt; long m0, hbase;
  if (!expert_of_tile(counts, mt, e, cnt, m0, hbase)) return;
  long n0 = (long)nt * 128;
  const int* idxe = idx + (long)e * B_;
  int wid = tid >> 6, lane = tid & 63;
  int wm = wid >> 1, wn = wid & 1;
  f32x4 acc[4][4];
#pragma unroll
  for (int m = 0; m < 4; m++)
#pragma unroll
    for (int n = 0; n < 4; n++) acc[m][n] = (f32x4){0.f, 0.f, 0.f, 0.f};
  int lr = lane & 15, lkg = lane >> 4;
  // staging: 128 rows x 4 chunks(16B) = 512 slots per tensor, 2 rounds each
  const u16* gA[2]; const u16* gB[2]; int lds_o[2];
  const u16* Bb = W1t + ((size_t)e * HE_ + n0) * D_;
#pragma unroll
  for (int i = 0; i < 2; i++) {
    int sidx = tid + i * 256;
    int r = sidx >> 2, j = sidx & 3;
    int so = ((j ^ ((r >> 1) & 3)) << 3);   // pre-swizzled source col (elems)
    int gi = (m0 + r < cnt) ? idxe[m0 + r] : 0;
    gA[i] = Xbs + (long)gi * 2048 + so;
    gB[i] = Bb + (long)r * D_ + so;
    lds_o[i] = sidx * 8;
  }
  // read-side frag byte offsets: row r, k-group lkg at slot lkg^((r>>1)&3)
  int foA[4], foB[4];
#pragma unroll
  for (int m = 0; m < 4; m++) {
    int r = wm * 64 + m * 16 + lr;
    foA[m] = r * 64 + (((lkg ^ ((r >> 1) & 3))) << 4);
  }
#pragma unroll
  for (int n = 0; n < 4; n++) {
    int r = wn * 64 + n * 16 + lr;
    foB[n] = r * 64 + (((lkg ^ ((r >> 1) & 3))) << 4);
  }
#define STAGE1(buf, k0) do { _Pragma("unroll") \
  for (int i_ = 0; i_ < 2; i_++) gload16(gA[i_] + (k0), &lA[buf][lds_o[i_]]); \
  _Pragma("unroll") \
  for (int i_ = 0; i_ < 2; i_++) gload16(gB[i_] + (k0), &lB[buf][lds_o[i_]]); \
  } while (0)
  STAGE1(0, 0);
  int cur = 0;
  constexpr int NT = D_ / 32;
  for (int t = 0; t < NT; ++t) {
    if (t + 1 < NT) {
      STAGE1(cur ^ 1, (t + 1) * 32);
      WAITVM(4);                 // tile t's 4 loads done; new 4 stay in flight
    } else {
      WAITVM(0);
    }
    __builtin_amdgcn_s_barrier();
    __builtin_amdgcn_sched_barrier(0);
    const char* pa = (const char*)lA[cur];
    const char* pb = (const char*)lB[cur];
    bf16x8 af[4], bfr[4];
#pragma unroll
    for (int m = 0; m < 4; m++)
      af[m] = *reinterpret_cast<const bf16x8*>(pa + foA[m]);
#pragma unroll
    for (int n = 0; n < 4; n++)
      bfr[n] = *reinterpret_cast<const bf16x8*>(pb + foB[n]);
    WAITLGKM0;
    __builtin_amdgcn_s_setprio(1);
#pragma unroll
    for (int m = 0; m < 4; m++)
#pragma unroll
      for (int n = 0; n < 4; n++)
        acc[m][n] = __builtin_amdgcn_mfma_f32_16x16x32_bf16(af[m], bfr[n], acc[m][n], 0, 0, 0);
    __builtin_amdgcn_s_setprio(0);
    __builtin_amdgcn_s_barrier();   // all waves' reads of buf[cur] complete
    __builtin_amdgcn_sched_barrier(0);
    cur ^= 1;
  }
#undef STAGE1
  int lq = lane >> 4;
#pragma unroll
  for (int m = 0; m < 4; m++) {
#pragma unroll
    for (int j = 0; j < 4; j++) {
      long lrow = m0 + wm * 64 + m * 16 + lq * 4 + j;
      if (lrow >= cnt) continue;
      int orow = idxe[lrow];
      float pw = P[(long)orow * NL_ + e];
#pragma unroll
      for (int n = 0; n < 4; n++) {
        long col = n0 + wn * 64 + n * 16 + lr;
        float g = gelu_fast(acc[m][n][j] + eb1[(size_t)e * HE_ + col]);
        Hall[(hbase + lrow) * HE_ + col] = f2bf(g * pw);
      }
    }
  }
}

// ======== grouped sparse expert GEMM2: counted-vmcnt double buffer =========
// A = Hall compact rows (K=2048), B = W2t[e][o][k] (ldb=2048 contiguous).
__global__ __launch_bounds__(256, 2) void gemme2_kernel(
    const u16* __restrict__ Hall, const u16* __restrict__ W2t,
    float* __restrict__ y, const int* __restrict__ idx,
    const int* __restrict__ counts) {
  __shared__ __attribute__((aligned(16))) u16 lA[2][128 * 64];
  __shared__ __attribute__((aligned(16))) u16 lB[2][128 * 64];
  int tid = threadIdx.x;
  int gid = blockIdx.x;
  int cpx = gridDim.x >> 3;
  gid = (gid & 7) * cpx + (gid >> 3);
  int mt = gid >> 3, nt = gid & 7;
  int e, cnt; long m0, hbase;
  if (!expert_of_tile(counts, mt, e, cnt, m0, hbase)) return;
  long n0 = (long)nt * 128;
  const int* idxe = idx + (long)e * B_;
  int wid = tid >> 6, lane = tid & 63;
  int wm = wid >> 1, wn = wid & 1;
  f32x4 acc[4][4];
#pragma unroll
  for (int m = 0; m < 4; m++)
#pragma unroll
    for (int n = 0; n < 4; n++) acc[m][n] = (f32x4){0.f, 0.f, 0.f, 0.f};
  int lr = lane & 15, lkg = lane >> 4;
  const u16* Ab = Hall + (hbase + m0) * HE_;
  const u16* Bb = W2t + ((size_t)e * O_ + n0) * HE_;
  const u16* gA[4]; const u16* gB[4]; int lds_o[4];
#pragma unroll
  for (int i = 0; i < 4; i++) {
    int sidx = tid + i * 256;
    int r = sidx >> 3, j = sidx & 7;
    int so = ((j ^ (r & 7)) << 3);
    gA[i] = Ab + (long)r * HE_ + so;
    gB[i] = Bb + (long)r * HE_ + so;
    lds_o[i] = sidx * 8;
  }
  int foA[4][2], foB[4][2];
#pragma unroll
  for (int m = 0; m < 4; m++) {
    int r = wm * 64 + m * 16 + lr;
#pragma unroll
    for (int kk = 0; kk < 2; kk++)
      foA[m][kk] = r * 128 + ((((kk * 4 + lkg) ^ (r & 7))) << 4);
  }
#pragma unroll
  for (int n = 0; n < 4; n++) {
    int r = wn * 64 + n * 16 + lr;
#pragma unroll
    for (int kk = 0; kk < 2; kk++)
      foB[n][kk] = r * 128 + ((((kk * 4 + lkg) ^ (r & 7))) << 4);
  }
#define STAGE2(buf, k0) do { _Pragma("unroll") \
  for (int i_ = 0; i_ < 4; i_++) gload16(gA[i_] + (k0), &lA[buf][lds_o[i_]]); \
  _Pragma("unroll") \
  for (int i_ = 0; i_ < 4; i_++) gload16(gB[i_] + (k0), &lB[buf][lds_o[i_]]); \
  } while (0)
  STAGE2(0, 0);
  int cur = 0;
  constexpr int NT = HE_ / 64;
  for (int t = 0; t < NT; ++t) {
    if (t + 1 < NT) {
      STAGE2(cur ^ 1, (t + 1) * 64);
      WAITVM(8);                 // tile t's 8 loads done; new 8 stay in flight
    } else {
      WAITVM(0);
    }
    __builtin_amdgcn_s_barrier();
    __builtin_amdgcn_sched_barrier(0);
    const char* pa = (const char*)lA[cur];
    const char* pb = (const char*)lB[cur];
    bf16x8 af[4][2], bfr[4][2];
#pragma unroll
    for (int m = 0; m < 4; m++) {
      af[m][0] = *reinterpret_cast<const bf16x8*>(pa + foA[m][0]);
      af[m][1] = *reinterpret_cast<const bf16x8*>(pa + foA[m][1]);
    }
#pragma unroll
    for (int n = 0; n < 4; n++) {
      bfr[n][0] = *reinterpret_cast<const bf16x8*>(pb + foB[n][0]);
      bfr[n][1] = *reinterpret_cast<const bf16x8*>(pb + foB[n][1]);
    }
    WAITLGKM0;
    __builtin_amdgcn_s_setprio(1);
#pragma unroll
    for (int m = 0; m < 4; m++)
#pragma unroll
      for (int n = 0; n < 4; n++) {
        acc[m][n] = __builtin_amdgcn_mfma_f32_16x16x32_bf16(af[m][0], bfr[n][0], acc[m][n], 0, 0, 0);
        acc[m][n] = __builtin_amdgcn_mfma_f32_16x16x32_bf16(af[m][1], bfr[n][1], acc[m][n], 0, 0, 0);
      }
    __builtin_amdgcn_s_setprio(0);
    __builtin_amdgcn_s_barrier();   // all waves' reads of buf[cur] complete
    __builtin_amdgcn_sched_barrier(0);
    cur ^= 1;
  }
#undef STAGE2
  int lq = lane >> 4;
#pragma unroll
  for (int m = 0; m < 4; m++) {
#pragma unroll
    for (int j = 0; j < 4; j++) {
      long lrow = m0 + wm * 64 + m * 16 + lq * 4 + j;
      if (lrow >= cnt) continue;
      long orow = idxe[lrow];
#pragma unroll
      for (int n = 0; n < 4; n++) {
        long col = n0 + wn * 64 + n * 16 + lr;
        unsafeAtomicAdd(&y[orow * O_ + col], acc[m][n][j]);
      }
    }
  }
}

extern "C" void kernel_launch(void* const* d_in, const int* in_sizes, int n_in,
                              void* d_out, int out_size, void* d_ws, size_t ws_size,
                              hipStream_t stream) {
  (void)in_sizes; (void)n_in; (void)out_size; (void)ws_size;
  const float* x   = (const float*)d_in[0];
  const float* rW1 = (const float*)d_in[1];
  const float* rb1 = (const float*)d_in[2];
  const float* rW2 = (const float*)d_in[3];
  const float* rb2 = (const float*)d_in[4];
  const float* eW1 = (const float*)d_in[5];
  const float* eb1 = (const float*)d_in[6];
  const float* eW2 = (const float*)d_in[7];
  const float* eb2 = (const float*)d_in[8];
  const int*  topk = (const int*)d_in[9];
  float* y = (float*)d_out;
  float* P = y + (size_t)B_ * O_;   // leaf_probs live in d_out tail

  // ws layout (high-water ~239 MiB, proven to fit):
  char* ws = (char*)d_ws;
  u16*  Xbs = (u16*)ws;                                   // 32 MiB [hi|lo]
  u16*  W1t = (u16*)(ws + 33554432);                      // 32 MiB
  u16*  W2t = (u16*)(ws + 67108864);                      // 32 MiB [e][o][k]
  int*  idx    = (int*)(ws + 100663296);                  // 256 KiB
  int*  counts = (int*)(ws + 100925440);                  // 32 B
  char* hreg   = ws + 100925952;                          // Hall region
  u16*  Hall = (u16*)hreg;                                // 33792x2048 bf16
  u16*  Wr3  = (u16*)hreg;                                // dead before Hall
  float* H1p = (float*)(hreg + 2097152);                  // dead before Hall

  // fused prep: 4096 (W1t) + 4096 (W2t) + 8192 (Xbs) + 768 (Wr3) blocks
  prep_kernel<<<17152, 256, 0, stream>>>(x, rW1, eW1, eW2, Xbs, Wr3, W1t, W2t);
  router_gemm_kernel<<<512, 256, 0, stream>>>(Xbs, Wr3, H1p);
  router_logits_kernel<<<B_ / 256, 256, 0, stream>>>(H1p, rb1, rW2, rb2, topk, P);
  // fused tail: 8192 yinit blocks + 8 compact blocks
  tail_kernel<<<8200, 256, 0, stream>>>(P, eb2, y, idx, counts);

  // grouped sparse expert GEMMs (one dispatch each, full GPU)
  gemme1_kernel<<<MTMAX_ * 16, 256, 0, stream>>>(
      Xbs, W1t, eb1, P, Hall, idx, counts);
  gemme2_kernel<<<MTMAX_ * 8, 256, 0, stream>>>(
      Hall, W2t, y, idx, counts);
}

// Round 19
// 591.646 us; speedup vs baseline: 1.0714x; 1.0031x over previous
//
#include <hip/hip_runtime.h>
#include <hip/hip_bf16.h>
#include <cstdint>

// Problem dims (fixed by the reference)
#define B_   8192
#define D_   1024
#define O_   1024
#define HE_  2048
#define NN_  7     // decision nodes
#define NL_  8     // leaves / experts
#define HR_  32    // router hidden
#define RC_  224   // NN_*HR_
#define K3_  3072  // router split-GEMM K (hi|hi|lo)
#define MTMAX_ 264 // max total m-tiles over experts (topk=4: <=264)

typedef __attribute__((ext_vector_type(2))) float f32x2;
typedef __attribute__((ext_vector_type(4))) float f32x4;
typedef __attribute__((ext_vector_type(8))) short bf16x8;
typedef __attribute__((ext_vector_type(4))) unsigned short u16x4;
typedef unsigned short u16;
typedef unsigned int u32;

__device__ __forceinline__ u16 f2bf(float f) {
  __hip_bfloat16 h = __float2bfloat16(f);
  return *reinterpret_cast<u16*>(&h);
}
__device__ __forceinline__ float bf2f(u16 u) {
  u32 v = ((u32)u) << 16;
  return *reinterpret_cast<float*>(&v);
}
__device__ __forceinline__ float gelu_exact(float v) {
  return 0.5f * v * (1.0f + erff(v * 0.7071067811865475f));
}
// tanh-approx gelu (|err| ~3e-4 < bf16 rounding of H). Used ONLY on the
// continuous expert path (H) — router keeps exact erff (top-k decisions).
__device__ __forceinline__ float gelu_fast(float x) {
  float u = x * x;
  float z = x * (0.7978845608f + 0.0356774081f * u);   // c1*x + c1*c2*x^3
  float t = __expf(2.0f * z);                          // v_exp; inf/0 safe
  float th = 1.0f - 2.0f / (t + 1.0f);
  return 0.5f * x * (1.0f + th);
}
__device__ __forceinline__ void gload16(const void* g, void* l) {
  __builtin_amdgcn_global_load_lds(
      (const __attribute__((address_space(1))) void*)(uintptr_t)g,
      (__attribute__((address_space(3))) void*)(uintptr_t)l,
      16, 0, 0);
}
#define WAITVM(n) asm volatile("s_waitcnt vmcnt(" #n ")" ::: "memory")
#define WAITLGKM0 do { \
  asm volatile("s_waitcnt lgkmcnt(0)" ::: "memory"); \
  __builtin_amdgcn_sched_barrier(0); } while (0)

// scalar-only expert lookup from counts (no runtime-indexed array, rule #20)
__device__ __forceinline__ bool expert_of_tile(
    const int* __restrict__ counts, int mt,
    int& e, int& cnt, long& m0, long& hbase) {
  int tot = 0; e = -1; cnt = 0; int tofe = 0;
#pragma unroll
  for (int f = 0; f < NL_; f++) {
    int c = counts[f];
    int tl = (c + 127) >> 7;
    bool in = (e < 0) && (mt < tot + tl);
    if (in) { e = f; tofe = tot; cnt = c; }
    tot += tl;
  }
  if (e < 0) return false;
  m0 = (long)(mt - tofe) * 128;
  hbase = (long)tofe * 128;
  return true;
}

// ======== fused prep: transposes + x split + router weight pack ============
__global__ __launch_bounds__(256) void prep_kernel(
    const float* __restrict__ x, const float* __restrict__ rW1,
    const float* __restrict__ eW1, const float* __restrict__ eW2,
    u16* __restrict__ Xbs, u16* __restrict__ Wr3,
    u16* __restrict__ W1t, u16* __restrict__ W2t) {
  __shared__ __attribute__((aligned(16))) float tile[64][65];
  int bid = blockIdx.x;
  int t = threadIdx.x;
  if (bid < 8192) {
    const float* in; u16* out; int C, ldo; long in_e, out_e;
    int bx, by, bz;
    if (bid < 4096) {
      in = eW1; out = W1t; C = HE_; ldo = D_;
      in_e = (long)D_ * HE_; out_e = (long)HE_ * D_;
      bx = bid & 31; by = (bid >> 5) & 15; bz = bid >> 9;
    } else {
      int b = bid - 4096;
      in = eW2; out = W2t; C = O_; ldo = HE_;
      in_e = (long)HE_ * O_; out_e = (long)O_ * HE_;
      bx = b & 15; by = (b >> 4) & 31; bz = b >> 9;
    }
    const float* in_p = in + bz * in_e;
    u16* out_p = out + bz * out_e;
    int r0 = by * 64, c0 = bx * 64;
    int cc = t & 63, rbase = t >> 6;
#pragma unroll
    for (int i = 0; i < 16; i++) {
      int rr = rbase + i * 4;
      tile[rr][cc] = in_p[(long)(r0 + rr) * C + c0 + cc];
    }
    __syncthreads();
    int r2 = (t & 31) * 2, cj = t >> 5;
#pragma unroll
    for (int i = 0; i < 8; i++) {
      int c = cj * 8 + i;
      u32 u = (u32)f2bf(tile[r2][c]) | ((u32)f2bf(tile[r2 + 1][c]) << 16);
      *reinterpret_cast<u32*>(out_p + (long)(c0 + c) * ldo + r0 + r2) = u;
    }
  } else if (bid < 16384) {
    size_t i = ((size_t)(bid - 8192) * 256 + t) * 4;
    size_t row = i >> 10;
    int col = (int)(i & 1023);
    f32x4 f = *reinterpret_cast<const f32x4*>(x + i);
    u16x4 hi, lo;
#pragma unroll
    for (int j = 0; j < 4; j++) {
      hi[j] = f2bf(f[j]);
      lo[j] = f2bf(f[j] - bf2f(hi[j]));
    }
    u16* base = Xbs + row * 2048 + col;
    *reinterpret_cast<u16x4*>(base)        = hi;
    *reinterpret_cast<u16x4*>(base + 1024) = lo;
  } else {
    size_t i = ((size_t)(bid - 16384) * 256 + t) * 4;  // over 256*3072
    int c = (int)(i / K3_), k = (int)(i % K3_);
    int j = k >> 10, kk = k & 1023;
    u16x4 o;
    if (c < RC_) {
      int node = c >> 5, h = c & 31;
      const float* src = rW1 + ((size_t)node * 1024 + kk) * HR_ + h;
#pragma unroll
      for (int q = 0; q < 4; q++) {
        float f = src[q * HR_];
        u16 hi = f2bf(f);
        o[q] = (j == 1) ? f2bf(f - bf2f(hi)) : hi;
      }
    } else {
      o[0] = 0; o[1] = 0; o[2] = 0; o[3] = 0;
    }
    *reinterpret_cast<u16x4*>(Wr3 + i) = o;
  }
}

// ---- router GEMM, split-K=4: H1p[s] = Xbs(mapped) @ Wr3^T  (raw, no gelu) -
__global__ __launch_bounds__(256, 2) void router_gemm_kernel(
    const u16* __restrict__ Xbs, const u16* __restrict__ Bm,
    float* __restrict__ H1p) {
  __shared__ __attribute__((aligned(16))) u16 lA[128 * 32];
  __shared__ __attribute__((aligned(16))) u16 lB[128 * 32];
  int tid = threadIdx.x;
  int gid = blockIdx.x;
  int cpx = gridDim.x >> 3;
  gid = (gid & 7) * cpx + (gid >> 3);
  int s = gid >> 7;                  // split id 0..3
  int rem = gid & 127;
  int band = rem >> 4, inb = rem & 15;
  long m0 = (long)(band * 8 + (inb & 7)) * 128;
  long n0 = (long)(inb >> 3) * 128;
  int wid = tid >> 6, lane = tid & 63;
  int wm = wid >> 1, wn = wid & 1;
  f32x4 acc[4][4];
#pragma unroll
  for (int m = 0; m < 4; m++)
#pragma unroll
    for (int n = 0; n < 4; n++) acc[m][n] = (f32x4){0.f, 0.f, 0.f, 0.f};
  int lr = lane & 15, lk = (lane >> 4) * 8;
  int srow = tid >> 2, soff = (tid & 3) * 8;
  const u16* Bb = Bm + n0 * K3_;
  int kbeg = s * 768, kend = kbeg + 768;
  for (int k0 = kbeg; k0 < kend; k0 += 32) {
    int ca = (k0 < 1024) ? k0 : k0 - 1024;   // hi / hi / lo remap
    gload16(Xbs + (m0 + srow) * 2048 + ca + soff, &lA[tid * 8]);
    gload16(Xbs + (m0 + 64 + srow) * 2048 + ca + soff, &lA[(256 + tid) * 8]);
    gload16(Bb + (long)srow * K3_ + k0 + soff, &lB[tid * 8]);
    gload16(Bb + (long)(64 + srow) * K3_ + k0 + soff, &lB[(256 + tid) * 8]);
    __syncthreads();
    bf16x8 af[4], bfr[4];
#pragma unroll
    for (int m = 0; m < 4; m++)
      af[m] = *reinterpret_cast<const bf16x8*>(&lA[(wm * 64 + m * 16 + lr) * 32 + lk]);
#pragma unroll
    for (int n = 0; n < 4; n++)
      bfr[n] = *reinterpret_cast<const bf16x8*>(&lB[(wn * 64 + n * 16 + lr) * 32 + lk]);
#pragma unroll
    for (int m = 0; m < 4; m++)
#pragma unroll
      for (int n = 0; n < 4; n++)
        acc[m][n] = __builtin_amdgcn_mfma_f32_16x16x32_bf16(af[m], bfr[n], acc[m][n], 0, 0, 0);
    __syncthreads();
  }
  int lq = lane >> 4;
#pragma unroll
  for (int m = 0; m < 4; m++)
#pragma unroll
    for (int n = 0; n < 4; n++)
#pragma unroll
      for (int j = 0; j < 4; j++) {
        long row = m0 + wm * 64 + m * 16 + lq * 4 + j;
        long col = n0 + wn * 64 + n * 16 + lr;
        if (col < RC_)
          H1p[((long)s * B_ + row) * RC_ + col] = acc[m][n][j];
      }
}

// -------- router layer 2: sum split-K partials + bias + gelu, softmax, -----
// NOTE: keeps EXACT erff gelu — feeds top-k decisions (discontinuous).
__global__ __launch_bounds__(256) void router_logits_kernel(
    const float* __restrict__ H1p, const float* __restrict__ rb1,
    const float* __restrict__ rW2, const float* __restrict__ rb2,
    const int* __restrict__ topk_ptr, float* __restrict__ P) {
  int b = blockIdx.x * 256 + threadIdx.x;
  float dec[NN_][2];
#pragma unroll
  for (int n = 0; n < NN_; n++) {
    float l0 = rb2[n * 2], l1 = rb2[n * 2 + 1];
#pragma unroll
    for (int r4 = 0; r4 < HR_; r4 += 4) {
      int c = n * HR_ + r4;
      f32x4 hs = *reinterpret_cast<const f32x4*>(&H1p[((long)0 * B_ + b) * RC_ + c]);
#pragma unroll
      for (int s = 1; s < 4; s++)
        hs += *reinterpret_cast<const f32x4*>(&H1p[((long)s * B_ + b) * RC_ + c]);
      f32x4 bv = *reinterpret_cast<const f32x4*>(rb1 + c);
#pragma unroll
      for (int j = 0; j < 4; j++) {
        float hv = gelu_exact(hs[j] + bv[j]);
        l0 += hv * rW2[(c + j) * 2];
        l1 += hv * rW2[(c + j) * 2 + 1];
      }
    }
    float mx = fmaxf(l0, l1);
    float e0 = expf(l0 - mx), e1 = expf(l1 - mx);
    float sm = e0 + e1;
    dec[n][0] = e0 / sm; dec[n][1] = e1 / sm;
  }
  float v[NL_];
#pragma unroll
  for (int L = 0; L < NL_; L++)
    v[L] = dec[0][L >> 2] * dec[1 + (L >> 2)][(L >> 1) & 1] * dec[3 + (L >> 1)][L & 1];
  int tk = *topk_ptr;
  float p[NL_];
  if (tk < NL_) {
    float s = 0.f;
    bool keep[NL_];
#pragma unroll
    for (int e = 0; e < NL_; e++) {
      int rank = 0;
#pragma unroll
      for (int j = 0; j < NL_; j++)
        rank += ((v[j] > v[e]) || (v[j] == v[e] && j < e)) ? 1 : 0;
      keep[e] = rank < tk;
      if (keep[e]) s += v[e];
    }
    float inv = 1.f / (s + 1e-8f);
#pragma unroll
    for (int e = 0; e < NL_; e++) p[e] = keep[e] ? v[e] * inv : 0.f;
  } else {
#pragma unroll
    for (int e = 0; e < NL_; e++) p[e] = v[e];
  }
#pragma unroll
  for (int e = 0; e < NL_; e++) P[(long)b * NL_ + e] = p[e];
}

// ======== fused tail: yinit (blocks 0..8191) + compact (blocks 8192..8199) =
__global__ __launch_bounds__(256) void tail_kernel(
    const float* __restrict__ P, const float* __restrict__ eb2,
    float* __restrict__ y, int* __restrict__ idx, int* __restrict__ counts) {
  __shared__ int wsum[4];
  __shared__ int sbase;
  int t = threadIdx.x;
  if (blockIdx.x < 8192) {
    size_t i = ((size_t)blockIdx.x * 256 + t) * 4;
    size_t row = i >> 10;
    int col = (int)(i & 1023);
    f32x4 s = (f32x4){0.f, 0.f, 0.f, 0.f};
#pragma unroll
    for (int e = 0; e < NL_; e++) {
      float pe = P[row * NL_ + e];
      f32x4 w = *reinterpret_cast<const f32x4*>(eb2 + (size_t)e * O_ + col);
      s += w * pe;
    }
    *reinterpret_cast<f32x4*>(y + i) = s;
  } else {
    int e = blockIdx.x - 8192;
    int wave = t >> 6, lane = t & 63;
    if (t == 0) sbase = 0;
    __syncthreads();
    for (int c0 = 0; c0 < B_; c0 += 256) {
      int r = c0 + t;
      bool f = P[(long)r * NL_ + e] > 0.f;
      unsigned long long mask = __ballot(f);
      int intra = __popcll(mask & ((1ULL << lane) - 1ULL));
      if (lane == 0) wsum[wave] = __popcll(mask);
      __syncthreads();
      int wpre = 0;
#pragma unroll
      for (int w = 0; w < 4; w++) wpre += (w < wave) ? wsum[w] : 0;
      int tot = wsum[0] + wsum[1] + wsum[2] + wsum[3];
      if (f) idx[(long)e * B_ + sbase + wpre + intra] = r;
      __syncthreads();
      if (t == 0) sbase += tot;
      __syncthreads();
    }
    if (t == 0) counts[e] = sbase;
  }
}

// ======== grouped sparse expert GEMM1: BK=32 dbuf, 2x unrolled (static buf) =
// 128x128 tile, 4 waves 2x2, 32KB LDS, counted vmcnt. K-loop unrolled by 2
// with STATICALLY-NAMED buffers so LDS bases are compile-time constants
// (ds_read offset-folding; no runtime cur-select VALU). gelu_fast epilogue.
__global__ __launch_bounds__(256, 2) void gemme1_kernel(
    const u16* __restrict__ Xbs, const u16* __restrict__ W1t,
    const float* __restrict__ eb1, const float* __restrict__ P,
    u16* __restrict__ Hall, const int* __restrict__ idx,
    const int* __restrict__ counts) {
  __shared__ __attribute__((aligned(16))) u16 lA0[128 * 32];
  __shared__ __attribute__((aligned(16))) u16 lA1[128 * 32];
  __shared__ __attribute__((aligned(16))) u16 lB0[128 * 32];
  __shared__ __attribute__((aligned(16))) u16 lB1[128 * 32];
  int tid = threadIdx.x;
  int gid = blockIdx.x;
  int cpx = gridDim.x >> 3;
  gid = (gid & 7) * cpx + (gid >> 3);      // XCD swizzle (grid%8==0)
  int mt = gid >> 4, nt = gid & 15;
  int e, cnt; long m0, hbase;
  if (!expert_of_tile(counts, mt, e, cnt, m0, hbase)) return;
  long n0 = (long)nt * 128;
  const int* idxe = idx + (long)e * B_;
  int wid = tid >> 6, lane = tid & 63;
  int wm = wid >> 1, wn = wid & 1;
  f32x4 acc[4][4];
#pragma unroll
  for (int m = 0; m < 4; m++)
#pragma unroll
    for (int n = 0; n < 4; n++) acc[m][n] = (f32x4){0.f, 0.f, 0.f, 0.f};
  int lr = lane & 15, lkg = lane >> 4;
  // staging: 128 rows x 4 chunks(16B) = 512 slots per tensor, 2 rounds each
  const u16* gA[2]; const u16* gB[2]; int lds_o[2];
  const u16* Bb = W1t + ((size_t)e * HE_ + n0) * D_;
#pragma unroll
  for (int i = 0; i < 2; i++) {
    int sidx = tid + i * 256;
    int r = sidx >> 2, j = sidx & 3;
    int so = ((j ^ ((r >> 1) & 3)) << 3);   // pre-swizzled source col (elems)
    int gi = (m0 + r < cnt) ? idxe[m0 + r] : 0;
    gA[i] = Xbs + (long)gi * 2048 + so;
    gB[i] = Bb + (long)r * D_ + so;
    lds_o[i] = sidx * 8;
  }
  // read-side frag byte offsets: row r, k-group lkg at slot lkg^((r>>1)&3)
  int foA[4], foB[4];
#pragma unroll
  for (int m = 0; m < 4; m++) {
    int r = wm * 64 + m * 16 + lr;
    foA[m] = r * 64 + (((lkg ^ ((r >> 1) & 3))) << 4);
  }
#pragma unroll
  for (int n = 0; n < 4; n++) {
    int r = wn * 64 + n * 16 + lr;
    foB[n] = r * 64 + (((lkg ^ ((r >> 1) & 3))) << 4);
  }
#define STAGE1(bufA, bufB, k0) do { _Pragma("unroll") \
  for (int i_ = 0; i_ < 2; i_++) gload16(gA[i_] + (k0), &bufA[lds_o[i_]]); \
  _Pragma("unroll") \
  for (int i_ = 0; i_ < 2; i_++) gload16(gB[i_] + (k0), &bufB[lds_o[i_]]); \
  } while (0)
#define BODY1(bufA, bufB) do { \
  const char* pa_ = (const char*)bufA; \
  const char* pb_ = (const char*)bufB; \
  bf16x8 af_[4], bfr_[4]; \
  _Pragma("unroll") \
  for (int m_ = 0; m_ < 4; m_++) \
    af_[m_] = *reinterpret_cast<const bf16x8*>(pa_ + foA[m_]); \
  _Pragma("unroll") \
  for (int n_ = 0; n_ < 4; n_++) \
    bfr_[n_] = *reinterpret_cast<const bf16x8*>(pb_ + foB[n_]); \
  WAITLGKM0; \
  __builtin_amdgcn_s_setprio(1); \
  _Pragma("unroll") \
  for (int m_ = 0; m_ < 4; m_++) \
    _Pragma("unroll") \
    for (int n_ = 0; n_ < 4; n_++) \
      acc[m_][n_] = __builtin_amdgcn_mfma_f32_16x16x32_bf16(af_[m_], bfr_[n_], acc[m_][n_], 0, 0, 0); \
  __builtin_amdgcn_s_setprio(0); \
  __builtin_amdgcn_s_barrier(); \
  __builtin_amdgcn_sched_barrier(0); } while (0)
  // NT = 32 (even). Prologue: tile 0 -> buf0.
  STAGE1(lA0, lB0, 0);
  constexpr int NT = D_ / 32;
  for (int t = 0; t < NT; t += 2) {
    // ---- tile t (buf0); stage t+1 -> buf1 (t+1 < NT always: NT even) ----
    STAGE1(lA1, lB1, (t + 1) * 32);
    WAITVM(4);
    __builtin_amdgcn_s_barrier();
    __builtin_amdgcn_sched_barrier(0);
    BODY1(lA0, lB0);
    // ---- tile t+1 (buf1); stage t+2 -> buf0 unless done ----
    if (t + 2 < NT) {
      STAGE1(lA0, lB0, (t + 2) * 32);
      WAITVM(4);
    } else {
      WAITVM(0);
    }
    __builtin_amdgcn_s_barrier();
    __builtin_amdgcn_sched_barrier(0);
    BODY1(lA1, lB1);
  }
#undef STAGE1
#undef BODY1
  int lq = lane >> 4;
#pragma unroll
  for (int m = 0; m < 4; m++) {
#pragma unroll
    for (int j = 0; j < 4; j++) {
      long lrow = m0 + wm * 64 + m * 16 + lq * 4 + j;
      if (lrow >= cnt) continue;
      int orow = idxe[lrow];
      float pw = P[(long)orow * NL_ + e];
#pragma unroll
      for (int n = 0; n < 4; n++) {
        long col = n0 + wn * 64 + n * 16 + lr;
        float g = gelu_fast(acc[m][n][j] + eb1[(size_t)e * HE_ + col]);
        Hall[(hbase + lrow) * HE_ + col] = f2bf(g * pw);
      }
    }
  }
}

// ======== grouped sparse expert GEMM2: BK=64 dbuf, 2x unrolled (static buf) =
// A = Hall compact rows (K=2048), B = W2t[e][o][k] (ldb=2048 contiguous).
__global__ __launch_bounds__(256, 2) void gemme2_kernel(
    const u16* __restrict__ Hall, const u16* __restrict__ W2t,
    float* __restrict__ y, const int* __restrict__ idx,
    const int* __restrict__ counts) {
  __shared__ __attribute__((aligned(16))) u16 lA0[128 * 64];
  __shared__ __attribute__((aligned(16))) u16 lA1[128 * 64];
  __shared__ __attribute__((aligned(16))) u16 lB0[128 * 64];
  __shared__ __attribute__((aligned(16))) u16 lB1[128 * 64];
  int tid = threadIdx.x;
  int gid = blockIdx.x;
  int cpx = gridDim.x >> 3;
  gid = (gid & 7) * cpx + (gid >> 3);
  int mt = gid >> 3, nt = gid & 7;
  int e, cnt; long m0, hbase;
  if (!expert_of_tile(counts, mt, e, cnt, m0, hbase)) return;
  long n0 = (long)nt * 128;
  const int* idxe = idx + (long)e * B_;
  int wid = tid >> 6, lane = tid & 63;
  int wm = wid >> 1, wn = wid & 1;
  f32x4 acc[4][4];
#pragma unroll
  for (int m = 0; m < 4; m++)
#pragma unroll
    for (int n = 0; n < 4; n++) acc[m][n] = (f32x4){0.f, 0.f, 0.f, 0.f};
  int lr = lane & 15, lkg = lane >> 4;
  const u16* Ab = Hall + (hbase + m0) * HE_;
  const u16* Bb = W2t + ((size_t)e * O_ + n0) * HE_;
  const u16* gA[4]; const u16* gB[4]; int lds_o[4];
#pragma unroll
  for (int i = 0; i < 4; i++) {
    int sidx = tid + i * 256;
    int r = sidx >> 3, j = sidx & 7;
    int so = ((j ^ (r & 7)) << 3);
    gA[i] = Ab + (long)r * HE_ + so;
    gB[i] = Bb + (long)r * HE_ + so;
    lds_o[i] = sidx * 8;
  }
  int foA[4][2], foB[4][2];
#pragma unroll
  for (int m = 0; m < 4; m++) {
    int r = wm * 64 + m * 16 + lr;
#pragma unroll
    for (int kk = 0; kk < 2; kk++)
      foA[m][kk] = r * 128 + ((((kk * 4 + lkg) ^ (r & 7))) << 4);
  }
#pragma unroll
  for (int n = 0; n < 4; n++) {
    int r = wn * 64 + n * 16 + lr;
#pragma unroll
    for (int kk = 0; kk < 2; kk++)
      foB[n][kk] = r * 128 + ((((kk * 4 + lkg) ^ (r & 7))) << 4);
  }
#define STAGE2(bufA, bufB, k0) do { _Pragma("unroll") \
  for (int i_ = 0; i_ < 4; i_++) gload16(gA[i_] + (k0), &bufA[lds_o[i_]]); \
  _Pragma("unroll") \
  for (int i_ = 0; i_ < 4; i_++) gload16(gB[i_] + (k0), &bufB[lds_o[i_]]); \
  } while (0)
#define BODY2(bufA, bufB) do { \
  const char* pa_ = (const char*)bufA; \
  const char* pb_ = (const char*)bufB; \
  bf16x8 af_[4][2], bfr_[4][2]; \
  _Pragma("unroll") \
  for (int m_ = 0; m_ < 4; m_++) { \
    af_[m_][0] = *reinterpret_cast<const bf16x8*>(pa_ + foA[m_][0]); \
    af_[m_][1] = *reinterpret_cast<const bf16x8*>(pa_ + foA[m_][1]); \
  } \
  _Pragma("unroll") \
  for (int n_ = 0; n_ < 4; n_++) { \
    bfr_[n_][0] = *reinterpret_cast<const bf16x8*>(pb_ + foB[n_][0]); \
    bfr_[n_][1] = *reinterpret_cast<const bf16x8*>(pb_ + foB[n_][1]); \
  } \
  WAITLGKM0; \
  __builtin_amdgcn_s_setprio(1); \
  _Pragma("unroll") \
  for (int m_ = 0; m_ < 4; m_++) \
    _Pragma("unroll") \
    for (int n_ = 0; n_ < 4; n_++) { \
      acc[m_][n_] = __builtin_amdgcn_mfma_f32_16x16x32_bf16(af_[m_][0], bfr_[n_][0], acc[m_][n_], 0, 0, 0); \
      acc[m_][n_] = __builtin_amdgcn_mfma_f32_16x16x32_bf16(af_[m_][1], bfr_[n_][1], acc[m_][n_], 0, 0, 0); \
    } \
  __builtin_amdgcn_s_setprio(0); \
  __builtin_amdgcn_s_barrier(); \
  __builtin_amdgcn_sched_barrier(0); } while (0)
  // NT = 32 (even). Prologue: tile 0 -> buf0.
  STAGE2(lA0, lB0, 0);
  constexpr int NT = HE_ / 64;
  for (int t = 0; t < NT; t += 2) {
    // ---- tile t (buf0); stage t+1 -> buf1 ----
    STAGE2(lA1, lB1, (t + 1) * 64);
    WAITVM(8);
    __builtin_amdgcn_s_barrier();
    __builtin_amdgcn_sched_barrier(0);
    BODY2(lA0, lB0);
    // ---- tile t+1 (buf1); stage t+2 -> buf0 unless done ----
    if (t + 2 < NT) {
      STAGE2(lA0, lB0, (t + 2) * 64);
      WAITVM(8);
    } else {
      WAITVM(0);
    }
    __builtin_amdgcn_s_barrier();
    __builtin_amdgcn_sched_barrier(0);
    BODY2(lA1, lB1);
  }
#undef STAGE2
#undef BODY2
  int lq = lane >> 4;
#pragma unroll
  for (int m = 0; m < 4; m++) {
#pragma unroll
    for (int j = 0; j < 4; j++) {
      long lrow = m0 + wm * 64 + m * 16 + lq * 4 + j;
      if (lrow >= cnt) continue;
      long orow = idxe[lrow];
#pragma unroll
      for (int n = 0; n < 4; n++) {
        long col = n0 + wn * 64 + n * 16 + lr;
        unsafeAtomicAdd(&y[orow * O_ + col], acc[m][n][j]);
      }
    }
  }
}

extern "C" void kernel_launch(void* const* d_in, const int* in_sizes, int n_in,
                              void* d_out, int out_size, void* d_ws, size_t ws_size,
                              hipStream_t stream) {
  (void)in_sizes; (void)n_in; (void)out_size; (void)ws_size;
  const float* x   = (const float*)d_in[0];
  const float* rW1 = (const float*)d_in[1];
  const float* rb1 = (const float*)d_in[2];
  const float* rW2 = (const float*)d_in[3];
  const float* rb2 = (const float*)d_in[4];
  const float* eW1 = (const float*)d_in[5];
  const float* eb1 = (const float*)d_in[6];
  const float* eW2 = (const float*)d_in[7];
  const float* eb2 = (const float*)d_in[8];
  const int*  topk = (const int*)d_in[9];
  float* y = (float*)d_out;
  float* P = y + (size_t)B_ * O_;   // leaf_probs live in d_out tail

  // ws layout (high-water ~239 MiB, proven to fit):
  char* ws = (char*)d_ws;
  u16*  Xbs = (u16*)ws;                                   // 32 MiB [hi|lo]
  u16*  W1t = (u16*)(ws + 33554432);                      // 32 MiB
  u16*  W2t = (u16*)(ws + 67108864);                      // 32 MiB [e][o][k]
  int*  idx    = (int*)(ws + 100663296);                  // 256 KiB
  int*  counts = (int*)(ws + 100925440);                  // 32 B
  char* hreg   = ws + 100925952;                          // Hall region
  u16*  Hall = (u16*)hreg;                                // 33792x2048 bf16
  u16*  Wr3  = (u16*)hreg;                                // dead before Hall
  float* H1p = (float*)(hreg + 2097152);                  // dead before Hall

  // fused prep: 4096 (W1t) + 4096 (W2t) + 8192 (Xbs) + 768 (Wr3) blocks
  prep_kernel<<<17152, 256, 0, stream>>>(x, rW1, eW1, eW2, Xbs, Wr3, W1t, W2t);
  router_gemm_kernel<<<512, 256, 0, stream>>>(Xbs, Wr3, H1p);
  router_logits_kernel<<<B_ / 256, 256, 0, stream>>>(H1p, rb1, rW2, rb2, topk, P);
  // fused tail: 8192 yinit blocks + 8 compact blocks
  tail_kernel<<<8200, 256, 0, stream>>>(P, eb2, y, idx, counts);

  // grouped sparse expert GEMMs (one dispatch each, full GPU)
  gemme1_kernel<<<MTMAX_ * 16, 256, 0, stream>>>(
      Xbs, W1t, eb1, P, Hall, idx, counts);
  gemme2_kernel<<<MTMAX_ * 8, 256, 0, stream>>>(
      Hall, W2t, y, idx, counts);
}